// Round 4
// baseline (706.720 us; speedup 1.0000x reference)
//
#include <hip/hip_runtime.h>
#include <hip/hip_bf16.h>

typedef _Float16 f16;
typedef __attribute__((ext_vector_type(8))) _Float16 f16x8;
typedef __attribute__((ext_vector_type(4))) _Float16 f16x4;
typedef __attribute__((ext_vector_type(4))) float f32x4;

#define DIM 1024
#define HEADS 16
#define DHEAD 64
#define MLPD 4096
#define NQ 16384
#define NW 1024
#define MCHUNK 32

#define WAITV(n) asm volatile("s_waitcnt vmcnt(" #n ")" ::: "memory")
#define WAITL0 asm volatile("s_waitcnt lgkmcnt(0)" ::: "memory")

// ---------------- async global->LDS (16B per lane) ----------------
__device__ __forceinline__ void glds16(const f16* g, f16* l) {
  __builtin_amdgcn_global_load_lds(
      (const __attribute__((address_space(1))) void*)g,
      (__attribute__((address_space(3))) void*)l, 16, 0, 0);
}

// ---------------- LayerNorm(1024): f32 in -> f16 out ----------------
__global__ __launch_bounds__(256) void ln_f16_k(
    const float* __restrict__ X, const float* __restrict__ w,
    const float* __restrict__ b, f16* __restrict__ O) {
  const int row = blockIdx.x;
  const int t = threadIdx.x;
  const float4 v = ((const float4*)(X + (long)row * DIM))[t];
  float s = v.x + v.y + v.z + v.w;
  float s2 = v.x * v.x + v.y * v.y + v.z * v.z + v.w * v.w;
#pragma unroll
  for (int m = 1; m < 64; m <<= 1) {
    s += __shfl_xor(s, m);
    s2 += __shfl_xor(s2, m);
  }
  __shared__ float ps[4], ps2[4];
  const int lane = t & 63, wid = t >> 6;
  if (lane == 0) { ps[wid] = s; ps2[wid] = s2; }
  __syncthreads();
  s = ps[0] + ps[1] + ps[2] + ps[3];
  s2 = ps2[0] + ps2[1] + ps2[2] + ps2[3];
  const float mu = s * (1.0f / DIM);
  const float inv = rsqrtf(s2 * (1.0f / DIM) - mu * mu + 1e-5f);
  const float4 wv = ((const float4*)w)[t];
  const float4 bv = ((const float4*)b)[t];
  f16x4 o;
  o[0] = (f16)((v.x - mu) * inv * wv.x + bv.x);
  o[1] = (f16)((v.y - mu) * inv * wv.y + bv.y);
  o[2] = (f16)((v.z - mu) * inv * wv.z + bv.z);
  o[3] = (f16)((v.w - mu) * inv * wv.w + bv.w);
  *(f16x4*)(O + (long)row * DIM + t * 4) = o;
}

// ---------------- transpose + cast f32[R][C] -> f16[C][R] ----------------
__global__ __launch_bounds__(256) void tcast_k(const float* __restrict__ X,
                                               f16* __restrict__ O, int R, int C) {
  __shared__ float tile[32][33];
  const int c0 = blockIdx.x * 32, r0 = blockIdx.y * 32;
  const int tx = threadIdx.x, ty = threadIdx.y;  // (32,8)
#pragma unroll
  for (int j = 0; j < 4; ++j)
    tile[ty + j * 8][tx] = X[(long)(r0 + ty + j * 8) * C + c0 + tx];
  __syncthreads();
#pragma unroll
  for (int j = 0; j < 4; ++j)
    O[(long)(c0 + ty + j * 8) * R + r0 + tx] = (f16)tile[tx][ty + j * 8];
}

// ---------------- M_h partials: Mp[h][ch] = sum_{n in chunk} khat^T v ------------
__global__ __launch_bounds__(256) void calc_m_part_k(const f16* __restrict__ kh,
                                                     const f16* __restrict__ v,
                                                     float* __restrict__ Mp) {
  const int h = blockIdx.x, ch = blockIdx.y;
  const int t = threadIdx.x;
  const int d1 = t >> 2;
  const int d2b = (t & 3) * 16;
  float acc[16] = {};
  const int n0 = ch * (NW / MCHUNK);
#pragma unroll 4
  for (int n = n0; n < n0 + NW / MCHUNK; ++n) {
    const float kv = (float)kh[(long)n * DIM + h * DHEAD + d1];
    const f16x8* vp = (const f16x8*)&v[(long)n * DIM + h * DHEAD + d2b];
    const f16x8 v0 = vp[0], v1 = vp[1];
#pragma unroll
    for (int j = 0; j < 8; ++j) acc[j] += kv * (float)v0[j];
#pragma unroll
    for (int j = 0; j < 8; ++j) acc[8 + j] += kv * (float)v1[j];
  }
  float* o = &Mp[((long)(h * MCHUNK + ch)) * 4096 + d1 * 64 + d2b];
#pragma unroll
  for (int j = 0; j < 16; ++j) o[j] = acc[j];
}

__global__ __launch_bounds__(256) void calc_m_reduce_k(const float* __restrict__ Mp,
                                                       float* __restrict__ Mo) {
  const int h = blockIdx.x;
  const int t = threadIdx.x;
#pragma unroll
  for (int e = t; e < 4096; e += 256) {
    float s = 0.f;
#pragma unroll
    for (int c = 0; c < MCHUNK; ++c)
      s += Mp[((long)(h * MCHUNK + c)) * 4096 + e];
    Mo[h * 4096 + e] = s;
  }
}

// ---------------- W_eff^T[j][i] = sum_d M[h(i)][i%64][d] * wo[h*64+d][j] ----------------
__global__ __launch_bounds__(256) void calc_wefft_k(const float* __restrict__ M,
                                                    const float* __restrict__ wo,
                                                    f16* __restrict__ Wt) {
  const int h = blockIdx.x, jt = blockIdx.y;
  const int t = threadIdx.x;
  const int jl = t & 63;
  const int il0 = (t >> 6) * 16;
  const int j = jt * 64 + jl;
  float acc[16] = {};
  for (int d = 0; d < DHEAD; ++d) {
    const float w = wo[(long)(h * DHEAD + d) * DIM + j];
    const float* mrow = &M[h * 4096 + il0 * 64 + d];
#pragma unroll
    for (int r = 0; r < 16; ++r) acc[r] += mrow[r * 64] * w;
  }
#pragma unroll
  for (int r = 0; r < 16; ++r)
    Wt[(long)j * DIM + h * DHEAD + il0 + r] = (f16)acc[r];
}

// ======================= 256x256 deep-pipelined GEMM ==========================
// C[M][N] = A[M][K](f16) @ Bt[N][K](f16)^T, BK=32, 512 thr = 8 waves (2Mx4N),
// per-wave 128x64 output (acc[8][4]), triple-buffered LDS (96KB), counted vmcnt.
// LDS swizzle (both-sides involution): col_byte ^= ((row>>1)&3)<<4.
enum {
  EPI_F16 = 0,       // f16 out
  EPI_L2N = 1,       // per-head l2norm, f16 out
  EPI_BIAS_RES = 2,  // f32 out = acc + bias + resid_f32
  EPI_GELU = 3       // f16 out = gelu(acc + bias)
};

template <int EPI>
__global__ __launch_bounds__(512, 2) void gemm256(
    const f16* __restrict__ A, const f16* __restrict__ Bt, int M, int N, int K,
    const float* __restrict__ bias, const float* resid, void* out) {
  // 3 bufs x (A: 256x32 = 8192 f16, B: 8192 f16) = 96 KB
  __shared__ __align__(16) f16 lds[3 * 16384];

  const int tid = threadIdx.x;
  const int lane = tid & 63;
  const int wid = tid >> 6;        // 0..7
  const int wm = wid >> 2;         // 0..1
  const int wn = wid & 3;          // 0..3

  // XCD-aware bijective blockIdx swizzle (all grids here are %8==0)
  int bm, bn;
  {
    const int total = gridDim.x * gridDim.y;
    const int orig = blockIdx.y * gridDim.x + blockIdx.x;
    int swz = orig;
    if ((total & 7) == 0) swz = (orig & 7) * (total >> 3) + (orig >> 3);
    bm = swz % gridDim.x;
    bn = swz / gridDim.x;
  }

  // --- staging addresses: thread t covers LDS row t>>2 (128 rows/call),
  // col pre-swizzled so linear LDS + swizzled ds_read line up.
  const int srow = tid >> 2;                                  // 0..127
  const int scol = (((tid & 3) ^ ((tid >> 3) & 3))) * 8;      // f16 col in [0,32)
  const f16* agp = A + (long)(bm * 256 + srow) * K + scol;
  const f16* bgp = Bt + (long)(bn * 256 + srow) * K + scol;
  const long h128 = (long)128 * K;

  auto STAGE = [&](int c, int t) {
    const long go = (long)t * 32;
    f16* base = &lds[c * 16384 + tid * 8];
    glds16(agp + go, base);
    glds16(agp + h128 + go, base + 4096);
    glds16(bgp + go, base + 8192);
    glds16(bgp + h128 + go, base + 12288);
  };

  const int NT = K >> 5;
  // prologue: stage tiles 0,1,2 (NT >= 3 for all our shapes)
  STAGE(0, 0);
  STAGE(1, 1);
  STAGE(2, 2);
  WAITV(8);  // tile 0 landed (tiles 1,2 may be in flight)
  __builtin_amdgcn_s_barrier();

  // per-lane fragment addresses (swizzle XOR is row-dependent only via (lane>>1)&3)
  const int l15 = lane & 15;
  const int kA = ((lane >> 4) * 8) ^ (((lane >> 1) & 3) * 8);  // f16 units
  const int abase = (wm * 128 + l15) * 32 + kA;
  const int bbase = (wn * 64 + l15) * 32 + kA;

  f32x4 acc[8][4] = {};

  for (int t = 0; t < NT; ++t) {
    const int c = t % 3;
    const f16* Ab = &lds[c * 16384];
    const f16* Bb = Ab + 8192;
    f16x8 a[8], b[4];
#pragma unroll
    for (int mi = 0; mi < 8; ++mi)
      a[mi] = *(const f16x8*)&Ab[abase + mi * 512];
#pragma unroll
    for (int nj = 0; nj < 4; ++nj)
      b[nj] = *(const f16x8*)&Bb[bbase + nj * 512];
    WAITL0;                              // own ds_reads done
    __builtin_amdgcn_sched_barrier(0);
    __builtin_amdgcn_s_barrier();        // B1: ALL waves done reading buf c
    if (t + 3 < NT) STAGE(c, t + 3);     // safe: everyone finished buf c
    __builtin_amdgcn_s_setprio(1);
#pragma unroll
    for (int mi = 0; mi < 8; ++mi)
#pragma unroll
      for (int nj = 0; nj < 4; ++nj)
        acc[mi][nj] = __builtin_amdgcn_mfma_f32_16x16x32_f16(a[mi], b[nj],
                                                             acc[mi][nj], 0, 0, 0);
    __builtin_amdgcn_s_setprio(0);
    // guarantee tile t+1 landed before next iteration's ds_reads (counted, never
    // 0 in steady state). Tail ladder as staging stops.
    if (t + 4 <= NT) WAITV(8);
    else if (t + 3 == NT) WAITV(4);
    else if (t + 2 == NT) WAITV(0);
    __builtin_amdgcn_s_barrier();        // B2: cross-wave landing guarantee
  }

  // epilogue: D row=(lane>>4)*4+i, col=lane&15 within each 16x16 frag
  const int r0 = bm * 256 + wm * 128;
  const int c0 = bn * 256 + wn * 64;   // == one head for EPI_L2N
  const int lr = (lane >> 4) * 4;
  const int lc = l15;

#pragma unroll
  for (int mi = 0; mi < 8; ++mi) {
#pragma unroll
    for (int i = 0; i < 4; ++i) {
      const long r = r0 + mi * 16 + lr + i;
      if (EPI == EPI_L2N) {
        float ss = 0.f;
#pragma unroll
        for (int nj = 0; nj < 4; ++nj) {
          const float x = acc[mi][nj][i];
          ss += x * x;
        }
        ss += __shfl_xor(ss, 1);
        ss += __shfl_xor(ss, 2);
        ss += __shfl_xor(ss, 4);
        ss += __shfl_xor(ss, 8);
        const float inv = 1.0f / fmaxf(sqrtf(ss), 1e-12f);
#pragma unroll
        for (int nj = 0; nj < 4; ++nj)
          ((f16*)out)[r * N + c0 + nj * 16 + lc] = (f16)(acc[mi][nj][i] * inv);
      } else if (EPI == EPI_F16) {
#pragma unroll
        for (int nj = 0; nj < 4; ++nj)
          ((f16*)out)[r * N + c0 + nj * 16 + lc] = (f16)acc[mi][nj][i];
      } else if (EPI == EPI_BIAS_RES) {
#pragma unroll
        for (int nj = 0; nj < 4; ++nj) {
          const long c = c0 + nj * 16 + lc;
          ((float*)out)[r * N + c] = acc[mi][nj][i] + bias[c] + resid[r * N + c];
        }
      } else {  // EPI_GELU (exact erf)
#pragma unroll
        for (int nj = 0; nj < 4; ++nj) {
          const long c = c0 + nj * 16 + lc;
          const float x = acc[mi][nj][i] + bias[c];
          ((f16*)out)[r * N + c] =
              (f16)(0.5f * x * (1.0f + erff(x * 0.70710678118654752f)));
        }
      }
    }
  }
}

extern "C" void kernel_launch(void* const* d_in, const int* in_sizes, int n_in,
                              void* d_out, int out_size, void* d_ws, size_t ws_size,
                              hipStream_t stream) {
  (void)in_sizes; (void)n_in; (void)out_size;
  const float* queries = (const float*)d_in[0];
  const float* prototypes = (const float*)d_in[1];
  const float* ln1_w = (const float*)d_in[2];
  const float* ln1_b = (const float*)d_in[3];
  const float* wq = (const float*)d_in[4];
  const float* wk = (const float*)d_in[5];
  const float* wv = (const float*)d_in[6];
  const float* wo = (const float*)d_in[7];
  const float* bo = (const float*)d_in[8];
  const float* ln2_w = (const float*)d_in[9];
  const float* ln2_b = (const float*)d_in[10];
  const float* w1 = (const float*)d_in[11];
  const float* b1 = (const float*)d_in[12];
  const float* w2 = (const float*)d_in[13];
  const float* b2 = (const float*)d_in[14];

  char* ws = (char*)d_ws;
  const size_t MB = 1024ull * 1024ull;
  if (ws_size < 176ull * MB) return;  // layout needs 176MB (harness gives >=192)

  // transient region (dead before MLP; G aliases it)
  f16* QN = (f16*)(ws + 0);             // 32MB [16384][1024]
  f16* QHAT = (f16*)(ws + 32 * MB);     // 32MB
  f16* PN = (f16*)(ws + 64 * MB);       // 2MB
  f16* WQT = (f16*)(ws + 66 * MB);      // 2MB
  f16* WKT = (f16*)(ws + 68 * MB);      // 2MB
  f16* WVT = (f16*)(ws + 70 * MB);      // 2MB
  f16* KHAT = (f16*)(ws + 72 * MB);     // 2MB
  f16* VBF = (f16*)(ws + 74 * MB);      // 2MB
  float* Mbuf = (float*)(ws + 76 * MB); // 256KB
  f16* WEFFT = (f16*)(ws + 77 * MB);    // 2MB
  float* Mpart = (float*)(ws + 0);      // 8MB, aliases QN (dead by then)
  // persistent region
  f16* G = (f16*)(ws + 0);              // 128MB [16384][4096], aliases transients
  f16* HBF = (f16*)(ws + 128 * MB);     // 32MB
  f16* W1T = (f16*)(ws + 160 * MB);     // 8MB [4096][1024]
  f16* W2T = (f16*)(ws + 168 * MB);     // 8MB [1024][4096]
  float* RES2 = (float*)d_out;          // residual2 lives in d_out (f32, 64MB)

  // LN1 + cast
  ln_f16_k<<<NQ, 256, 0, stream>>>(queries, ln1_w, ln1_b, QN);
  ln_f16_k<<<NW, 256, 0, stream>>>(prototypes, ln1_w, ln1_b, PN);
  // weight transpose-casts
  tcast_k<<<dim3(32, 32), dim3(32, 8), 0, stream>>>(wq, WQT, DIM, DIM);
  tcast_k<<<dim3(32, 32), dim3(32, 8), 0, stream>>>(wk, WKT, DIM, DIM);
  tcast_k<<<dim3(32, 32), dim3(32, 8), 0, stream>>>(wv, WVT, DIM, DIM);
  tcast_k<<<dim3(128, 32), dim3(32, 8), 0, stream>>>(w1, W1T, DIM, MLPD);
  tcast_k<<<dim3(32, 128), dim3(32, 8), 0, stream>>>(w2, W2T, MLPD, DIM);

  // projections (+fused per-head l2norm for q,k)
  gemm256<EPI_L2N><<<dim3(NQ / 256, DIM / 256), 512, 0, stream>>>(
      QN, WQT, NQ, DIM, DIM, nullptr, nullptr, QHAT);
  gemm256<EPI_L2N><<<dim3(NW / 256, DIM / 256), 512, 0, stream>>>(
      PN, WKT, NW, DIM, DIM, nullptr, nullptr, KHAT);
  gemm256<EPI_F16><<<dim3(NW / 256, DIM / 256), 512, 0, stream>>>(
      PN, WVT, NW, DIM, DIM, nullptr, nullptr, VBF);

  // attention collapse: M_h = khat^T v (split-K) ; W_eff^T = (blockdiag(M) @ wo)^T
  calc_m_part_k<<<dim3(HEADS, MCHUNK), 256, 0, stream>>>(KHAT, VBF, Mpart);
  calc_m_reduce_k<<<HEADS, 256, 0, stream>>>(Mpart, Mbuf);
  calc_wefft_k<<<dim3(HEADS, 16), 256, 0, stream>>>(Mbuf, wo, WEFFT);

  // attn-out + wo + bias + residual -> RES2 (f32, stored in d_out)
  gemm256<EPI_BIAS_RES><<<dim3(NQ / 256, DIM / 256), 512, 0, stream>>>(
      QHAT, WEFFT, NQ, DIM, DIM, bo, queries, RES2);

  // LN2 (reads d_out f32)
  ln_f16_k<<<NQ, 256, 0, stream>>>(RES2, ln2_w, ln2_b, HBF);

  // MLP, unchunked (G = 128MB)
  gemm256<EPI_GELU><<<dim3(NQ / 256, MLPD / 256), 512, 0, stream>>>(
      HBF, W1T, NQ, MLPD, DIM, b1, nullptr, G);
  gemm256<EPI_BIAS_RES><<<dim3(NQ / 256, DIM / 256), 512, 0, stream>>>(
      G, W2T, NQ, DIM, MLPD, b2, RES2, (float*)d_out);
}

// Round 5
// 693.116 us; speedup vs baseline: 1.0196x; 1.0196x over previous
//
#include <hip/hip_runtime.h>
#include <hip/hip_bf16.h>

typedef _Float16 f16;
typedef __attribute__((ext_vector_type(8))) _Float16 f16x8;
typedef __attribute__((ext_vector_type(4))) _Float16 f16x4;
typedef __attribute__((ext_vector_type(4))) float f32x4;

#define DIM 1024
#define HEADS 16
#define DHEAD 64
#define MLPD 4096
#define NQ 16384
#define NW 1024
#define MCHUNK 32

#define WAITV(n) asm volatile("s_waitcnt vmcnt(" #n ")" ::: "memory")
#define WAITL0 asm volatile("s_waitcnt lgkmcnt(0)" ::: "memory")

// ---------------- async global->LDS (16B per lane) ----------------
__device__ __forceinline__ void glds16(const f16* g, f16* l) {
  __builtin_amdgcn_global_load_lds(
      (const __attribute__((address_space(1))) void*)g,
      (__attribute__((address_space(3))) void*)l, 16, 0, 0);
}

// ---------------- LayerNorm(1024): f32 in -> f16 out ----------------
__global__ __launch_bounds__(256) void ln_f16_k(
    const float* __restrict__ X, const float* __restrict__ w,
    const float* __restrict__ b, f16* __restrict__ O) {
  const int row = blockIdx.x;
  const int t = threadIdx.x;
  const float4 v = ((const float4*)(X + (long)row * DIM))[t];
  float s = v.x + v.y + v.z + v.w;
  float s2 = v.x * v.x + v.y * v.y + v.z * v.z + v.w * v.w;
#pragma unroll
  for (int m = 1; m < 64; m <<= 1) {
    s += __shfl_xor(s, m);
    s2 += __shfl_xor(s2, m);
  }
  __shared__ float ps[4], ps2[4];
  const int lane = t & 63, wid = t >> 6;
  if (lane == 0) { ps[wid] = s; ps2[wid] = s2; }
  __syncthreads();
  s = ps[0] + ps[1] + ps[2] + ps[3];
  s2 = ps2[0] + ps2[1] + ps2[2] + ps2[3];
  const float mu = s * (1.0f / DIM);
  const float inv = rsqrtf(s2 * (1.0f / DIM) - mu * mu + 1e-5f);
  const float4 wv = ((const float4*)w)[t];
  const float4 bv = ((const float4*)b)[t];
  f16x4 o;
  o[0] = (f16)((v.x - mu) * inv * wv.x + bv.x);
  o[1] = (f16)((v.y - mu) * inv * wv.y + bv.y);
  o[2] = (f16)((v.z - mu) * inv * wv.z + bv.z);
  o[3] = (f16)((v.w - mu) * inv * wv.w + bv.w);
  *(f16x4*)(O + (long)row * DIM + t * 4) = o;
}

// ---------------- transpose + cast f32[R][C] -> f16[C][R] ----------------
__global__ __launch_bounds__(256) void tcast_k(const float* __restrict__ X,
                                               f16* __restrict__ O, int R, int C) {
  __shared__ float tile[32][33];
  const int c0 = blockIdx.x * 32, r0 = blockIdx.y * 32;
  const int tx = threadIdx.x, ty = threadIdx.y;  // (32,8)
#pragma unroll
  for (int j = 0; j < 4; ++j)
    tile[ty + j * 8][tx] = X[(long)(r0 + ty + j * 8) * C + c0 + tx];
  __syncthreads();
#pragma unroll
  for (int j = 0; j < 4; ++j)
    O[(long)(c0 + ty + j * 8) * R + r0 + tx] = (f16)tile[tx][ty + j * 8];
}

// ---------------- M_h partials: Mp[h][ch] = sum_{n in chunk} khat^T v ------------
__global__ __launch_bounds__(256) void calc_m_part_k(const f16* __restrict__ kh,
                                                     const f16* __restrict__ v,
                                                     float* __restrict__ Mp) {
  const int h = blockIdx.x, ch = blockIdx.y;
  const int t = threadIdx.x;
  const int d1 = t >> 2;
  const int d2b = (t & 3) * 16;
  float acc[16] = {};
  const int n0 = ch * (NW / MCHUNK);
#pragma unroll 4
  for (int n = n0; n < n0 + NW / MCHUNK; ++n) {
    const float kv = (float)kh[(long)n * DIM + h * DHEAD + d1];
    const f16x8* vp = (const f16x8*)&v[(long)n * DIM + h * DHEAD + d2b];
    const f16x8 v0 = vp[0], v1 = vp[1];
#pragma unroll
    for (int j = 0; j < 8; ++j) acc[j] += kv * (float)v0[j];
#pragma unroll
    for (int j = 0; j < 8; ++j) acc[8 + j] += kv * (float)v1[j];
  }
  float* o = &Mp[((long)(h * MCHUNK + ch)) * 4096 + d1 * 64 + d2b];
#pragma unroll
  for (int j = 0; j < 16; ++j) o[j] = acc[j];
}

__global__ __launch_bounds__(256) void calc_m_reduce_k(const float* __restrict__ Mp,
                                                       float* __restrict__ Mo) {
  const int h = blockIdx.x;
  const int t = threadIdx.x;
#pragma unroll
  for (int e = t; e < 4096; e += 256) {
    float s = 0.f;
#pragma unroll
    for (int c = 0; c < MCHUNK; ++c)
      s += Mp[((long)(h * MCHUNK + c)) * 4096 + e];
    Mo[h * 4096 + e] = s;
  }
}

// ---------------- W_eff^T[j][i] = sum_d M[h(i)][i%64][d] * wo[h*64+d][j] ----------------
__global__ __launch_bounds__(256) void calc_wefft_k(const float* __restrict__ M,
                                                    const float* __restrict__ wo,
                                                    f16* __restrict__ Wt) {
  const int h = blockIdx.x, jt = blockIdx.y;
  const int t = threadIdx.x;
  const int jl = t & 63;
  const int il0 = (t >> 6) * 16;
  const int j = jt * 64 + jl;
  float acc[16] = {};
  for (int d = 0; d < DHEAD; ++d) {
    const float w = wo[(long)(h * DHEAD + d) * DIM + j];
    const float* mrow = &M[h * 4096 + il0 * 64 + d];
#pragma unroll
    for (int r = 0; r < 16; ++r) acc[r] += mrow[r * 64] * w;
  }
#pragma unroll
  for (int r = 0; r < 16; ++r)
    Wt[(long)j * DIM + h * DHEAD + il0 + r] = (f16)acc[r];
}

// ======================= 256x256 8-phase GEMM (m201-style) ==========================
// C[M][N] = A[M][K](f16) @ Bt[N][K](f16)^T. BK=64, 512 thr = 8 waves (2Mx4N),
// per-wave 128x64 out (acc[8][4]). LDS 128KB = 2 bufs x {A[2][256][32], B[2][256][32]}
// (k-major slices). 4 phases per K-tile: (ks,mh) = (0,0),(0,1),(1,0),(1,1).
// Each phase: stage 2 glds into a barrier-freed 16KB region -> ds_read quadrant
// frags -> barrier -> lgkm(0) -> setprio(1) 16 MFMA setprio(0) -> [WAITV(8) on odd
// phases] -> barrier. Stage map (group g, tile t, buf b=t&1):
//   ph0: A.ks1(t+1)->buf^1   ph1: B.ks1(t+1)->buf^1
//   ph2: A.ks0(t+2)->buf     ph3: B.ks0(t+2)->buf
// All regions freed by preceding barriers; prefetch lead 5-6 phases; vmcnt counted.
enum {
  EPI_F16 = 0,       // f16 out
  EPI_L2N = 1,       // per-head l2norm, f16 out
  EPI_BIAS_RES = 2,  // f32 out = acc + bias + resid_f32
  EPI_GELU = 3       // f16 out = gelu(acc + bias)
};

template <int EPI>
__global__ __launch_bounds__(512, 2) void gemm256(
    const f16* __restrict__ A, const f16* __restrict__ Bt, int M, int N, int K,
    const float* __restrict__ bias, const float* resid, void* out) {
  // per buf (f16 units): A at 0 (ks*8192), B at 16384 (+ks*8192); buf stride 32768
  __shared__ __align__(16) f16 lds[65536];  // 128KB

  const int tid = threadIdx.x;
  const int lane = tid & 63;
  const int wid = tid >> 6;   // 0..7
  const int wm = wid >> 2;    // 0..1
  const int wn = wid & 3;     // 0..3
  const int l15 = lane & 15;

  // XCD-aware bijective blockIdx swizzle (all grids here are %8==0)
  int bm, bn;
  {
    const int total = gridDim.x * gridDim.y;
    const int orig = blockIdx.y * gridDim.x + blockIdx.x;
    int swz = orig;
    if ((total & 7) == 0) swz = (orig & 7) * (total >> 3) + (orig >> 3);
    bm = swz % gridDim.x;
    bn = swz / gridDim.x;
  }

  // staging: thread t -> row = c*128 + (t>>2), slot = t&3 within a 16KB region.
  // source col pre-XORed with ((row>>1)&3) = ((t>>3)&3) so linear LDS + XORed
  // ds_read line up (both-sides involution).
  const int scol8 = (((tid & 3) ^ ((tid >> 3) & 3))) * 8;
  const f16* aSrc = A + (long)(bm * 256 + (tid >> 2)) * K + scol8;
  const f16* bSrc = Bt + (long)(bn * 256 + (tid >> 2)) * K + scol8;
  const long hK = (long)128 * K;
  const int tid8 = tid * 8;

  // ds_read bases: slot XOR (lane>>4)^((l15>>1)&3)
  const int rslot8 = (((lane >> 4) ^ ((l15 >> 1) & 3))) * 8;
  const int aRdBase = (wm * 128 + l15) * 32 + rslot8;
  const int bRdBase = 16384 + (wn * 64 + l15) * 32 + rslot8;

  f32x4 acc[8][4] = {};
  const int NT = K >> 6;  // K-tiles of 64 (NT >= 16 for all launches here)

  // ---- prologue: t0.A.ks0, t0.B.ks0, t0.A.ks1, t0.B.ks1, t1.A.ks0, t1.B.ks0
  glds16(aSrc, &lds[tid8]);
  glds16(aSrc + hK, &lds[4096 + tid8]);
  glds16(bSrc, &lds[16384 + tid8]);
  glds16(bSrc + hK, &lds[16384 + 4096 + tid8]);
  glds16(aSrc + 32, &lds[8192 + tid8]);
  glds16(aSrc + hK + 32, &lds[8192 + 4096 + tid8]);
  glds16(bSrc + 32, &lds[24576 + tid8]);
  glds16(bSrc + hK + 32, &lds[24576 + 4096 + tid8]);
  glds16(aSrc + 64, &lds[32768 + tid8]);
  glds16(aSrc + hK + 64, &lds[32768 + 4096 + tid8]);
  glds16(bSrc + 64, &lds[32768 + 16384 + tid8]);
  glds16(bSrc + hK + 64, &lds[32768 + 16384 + 4096 + tid8]);
  WAITV(8);  // t0.ks0 (A+B) landed; t0.ks1 + t1.ks0 in flight
  __builtin_amdgcn_s_barrier();

#define PHASE_CORE(KS, MH, LOADB)                                        \
  {                                                                      \
    const f16* Ap = L + (KS)*8192 + aRdBase + (MH)*2048;                 \
    a[0] = *(const f16x8*)(Ap);                                          \
    a[1] = *(const f16x8*)(Ap + 512);                                    \
    a[2] = *(const f16x8*)(Ap + 1024);                                   \
    a[3] = *(const f16x8*)(Ap + 1536);                                   \
    if (LOADB) {                                                         \
      const f16* Bp = L + (KS)*8192 + bRdBase;                           \
      b[0] = *(const f16x8*)(Bp);                                        \
      b[1] = *(const f16x8*)(Bp + 512);                                  \
      b[2] = *(const f16x8*)(Bp + 1024);                                 \
      b[3] = *(const f16x8*)(Bp + 1536);                                 \
    }                                                                    \
    __builtin_amdgcn_s_barrier();                                        \
    WAITL0;                                                              \
    __builtin_amdgcn_sched_barrier(0);                                   \
    __builtin_amdgcn_s_setprio(1);                                       \
    _Pragma("unroll") for (int j = 0; j < 4; ++j)                        \
        _Pragma("unroll") for (int nj = 0; nj < 4; ++nj)                 \
            acc[(MH)*4 + j][nj] = __builtin_amdgcn_mfma_f32_16x16x32_f16(\
                a[j], b[nj], acc[(MH)*4 + j][nj], 0, 0, 0);              \
    __builtin_amdgcn_s_setprio(0);                                       \
  }

  for (int g = 0; g < NT; ++g) {
    f16* L = &lds[(g & 1) * 32768];
    f16* Lo = &lds[((g & 1) ^ 1) * 32768];
    const long ko1 = (long)(g + 1) * 64;
    const long ko2 = (long)(g + 2) * 64;
    const bool s1 = (g + 1) < NT, s2 = (g + 2) < NT;
    f16x8 a[4], b[4];

    // ---- phase 0: (ks0, mh0); stage A.ks1(t+1) -> buf^1
    if (s1) {
      glds16(aSrc + ko1 + 32, Lo + 8192 + tid8);
      glds16(aSrc + hK + ko1 + 32, Lo + 8192 + 4096 + tid8);
    }
    PHASE_CORE(0, 0, 1);
    __builtin_amdgcn_s_barrier();

    // ---- phase 1: (ks0, mh1); stage B.ks1(t+1) -> buf^1
    if (s1) {
      glds16(bSrc + ko1 + 32, Lo + 24576 + tid8);
      glds16(bSrc + hK + ko1 + 32, Lo + 24576 + 4096 + tid8);
    }
    PHASE_CORE(0, 1, 0);
    if (s1) { WAITV(8); } else { WAITV(0); }  // t.ks1 landed (for ph2)
    __builtin_amdgcn_s_barrier();

    // ---- phase 2: (ks1, mh0); stage A.ks0(t+2) -> buf (freed by ph1 barrier)
    if (s2) {
      glds16(aSrc + ko2, L + tid8);
      glds16(aSrc + hK + ko2, L + 4096 + tid8);
    }
    PHASE_CORE(1, 0, 1);
    __builtin_amdgcn_s_barrier();

    // ---- phase 3: (ks1, mh1); stage B.ks0(t+2) -> buf (freed by ph1 barrier)
    if (s2) {
      glds16(bSrc + ko2, L + 16384 + tid8);
      glds16(bSrc + hK + ko2, L + 16384 + 4096 + tid8);
    }
    PHASE_CORE(1, 1, 0);
    if (s2) { WAITV(8); } else if (s1) { WAITV(4); }  // t+1.ks0 landed
    __builtin_amdgcn_s_barrier();
  }
#undef PHASE_CORE

  // epilogue: D row=(lane>>4)*4+i, col=lane&15 within each 16x16 frag
  const int r0 = bm * 256 + wm * 128;
  const int c0 = bn * 256 + wn * 64;  // == one head for EPI_L2N
  const int lr = (lane >> 4) * 4;
  const int lc = l15;

#pragma unroll
  for (int mi = 0; mi < 8; ++mi) {
#pragma unroll
    for (int i = 0; i < 4; ++i) {
      const long r = r0 + mi * 16 + lr + i;
      if (EPI == EPI_L2N) {
        float ss = 0.f;
#pragma unroll
        for (int nj = 0; nj < 4; ++nj) {
          const float x = acc[mi][nj][i];
          ss += x * x;
        }
        ss += __shfl_xor(ss, 1);
        ss += __shfl_xor(ss, 2);
        ss += __shfl_xor(ss, 4);
        ss += __shfl_xor(ss, 8);
        const float inv = 1.0f / fmaxf(sqrtf(ss), 1e-12f);
#pragma unroll
        for (int nj = 0; nj < 4; ++nj)
          ((f16*)out)[r * N + c0 + nj * 16 + lc] = (f16)(acc[mi][nj][i] * inv);
      } else if (EPI == EPI_F16) {
#pragma unroll
        for (int nj = 0; nj < 4; ++nj)
          ((f16*)out)[r * N + c0 + nj * 16 + lc] = (f16)acc[mi][nj][i];
      } else if (EPI == EPI_BIAS_RES) {
#pragma unroll
        for (int nj = 0; nj < 4; ++nj) {
          const long c = c0 + nj * 16 + lc;
          ((float*)out)[r * N + c] = acc[mi][nj][i] + bias[c] + resid[r * N + c];
        }
      } else {  // EPI_GELU (exact erf)
#pragma unroll
        for (int nj = 0; nj < 4; ++nj) {
          const long c = c0 + nj * 16 + lc;
          const float x = acc[mi][nj][i] + bias[c];
          ((f16*)out)[r * N + c] =
              (f16)(0.5f * x * (1.0f + erff(x * 0.70710678118654752f)));
        }
      }
    }
  }
}

extern "C" void kernel_launch(void* const* d_in, const int* in_sizes, int n_in,
                              void* d_out, int out_size, void* d_ws, size_t ws_size,
                              hipStream_t stream) {
  (void)in_sizes; (void)n_in; (void)out_size;
  const float* queries = (const float*)d_in[0];
  const float* prototypes = (const float*)d_in[1];
  const float* ln1_w = (const float*)d_in[2];
  const float* ln1_b = (const float*)d_in[3];
  const float* wq = (const float*)d_in[4];
  const float* wk = (const float*)d_in[5];
  const float* wv = (const float*)d_in[6];
  const float* wo = (const float*)d_in[7];
  const float* bo = (const float*)d_in[8];
  const float* ln2_w = (const float*)d_in[9];
  const float* ln2_b = (const float*)d_in[10];
  const float* w1 = (const float*)d_in[11];
  const float* b1 = (const float*)d_in[12];
  const float* w2 = (const float*)d_in[13];
  const float* b2 = (const float*)d_in[14];

  char* ws = (char*)d_ws;
  const size_t MB = 1024ull * 1024ull;
  if (ws_size < 176ull * MB) return;  // layout needs 176MB

  // transient region (dead before MLP; G aliases it)
  f16* QN = (f16*)(ws + 0);             // 32MB [16384][1024]
  f16* QHAT = (f16*)(ws + 32 * MB);     // 32MB
  f16* PN = (f16*)(ws + 64 * MB);       // 2MB
  f16* WQT = (f16*)(ws + 66 * MB);      // 2MB
  f16* WKT = (f16*)(ws + 68 * MB);      // 2MB
  f16* WVT = (f16*)(ws + 70 * MB);      // 2MB
  f16* KHAT = (f16*)(ws + 72 * MB);     // 2MB
  f16* VBF = (f16*)(ws + 74 * MB);      // 2MB
  float* Mbuf = (float*)(ws + 76 * MB); // 256KB
  f16* WEFFT = (f16*)(ws + 77 * MB);    // 2MB
  float* Mpart = (float*)(ws + 0);      // 8MB, aliases QN (dead by then)
  // persistent region
  f16* G = (f16*)(ws + 0);              // 128MB [16384][4096], aliases transients
  f16* HBF = (f16*)(ws + 128 * MB);     // 32MB
  f16* W1T = (f16*)(ws + 160 * MB);     // 8MB [4096][1024]
  f16* W2T = (f16*)(ws + 168 * MB);     // 8MB [1024][4096]
  float* RES2 = (float*)d_out;          // residual2 lives in d_out (f32, 64MB)

  // LN1 + cast
  ln_f16_k<<<NQ, 256, 0, stream>>>(queries, ln1_w, ln1_b, QN);
  ln_f16_k<<<NW, 256, 0, stream>>>(prototypes, ln1_w, ln1_b, PN);
  // weight transpose-casts
  tcast_k<<<dim3(32, 32), dim3(32, 8), 0, stream>>>(wq, WQT, DIM, DIM);
  tcast_k<<<dim3(32, 32), dim3(32, 8), 0, stream>>>(wk, WKT, DIM, DIM);
  tcast_k<<<dim3(32, 32), dim3(32, 8), 0, stream>>>(wv, WVT, DIM, DIM);
  tcast_k<<<dim3(128, 32), dim3(32, 8), 0, stream>>>(w1, W1T, DIM, MLPD);
  tcast_k<<<dim3(32, 128), dim3(32, 8), 0, stream>>>(w2, W2T, MLPD, DIM);

  // projections (+fused per-head l2norm for q,k)
  gemm256<EPI_L2N><<<dim3(NQ / 256, DIM / 256), 512, 0, stream>>>(
      QN, WQT, NQ, DIM, DIM, nullptr, nullptr, QHAT);
  gemm256<EPI_L2N><<<dim3(NW / 256, DIM / 256), 512, 0, stream>>>(
      PN, WKT, NW, DIM, DIM, nullptr, nullptr, KHAT);
  gemm256<EPI_F16><<<dim3(NW / 256, DIM / 256), 512, 0, stream>>>(
      PN, WVT, NW, DIM, DIM, nullptr, nullptr, VBF);

  // attention collapse: M_h = khat^T v (split-K) ; W_eff^T = (blockdiag(M) @ wo)^T
  calc_m_part_k<<<dim3(HEADS, MCHUNK), 256, 0, stream>>>(KHAT, VBF, Mpart);
  calc_m_reduce_k<<<HEADS, 256, 0, stream>>>(Mpart, Mbuf);
  calc_wefft_k<<<dim3(HEADS, 16), 256, 0, stream>>>(Mbuf, wo, WEFFT);

  // attn-out + wo + bias + residual -> RES2 (f32, stored in d_out)
  gemm256<EPI_BIAS_RES><<<dim3(NQ / 256, DIM / 256), 512, 0, stream>>>(
      QHAT, WEFFT, NQ, DIM, DIM, bo, queries, RES2);

  // LN2 (reads d_out f32)
  ln_f16_k<<<NQ, 256, 0, stream>>>(RES2, ln2_w, ln2_b, HBF);

  // MLP, unchunked (G = 128MB)
  gemm256<EPI_GELU><<<dim3(NQ / 256, MLPD / 256), 512, 0, stream>>>(
      HBF, W1T, NQ, MLPD, DIM, b1, nullptr, G);
  gemm256<EPI_BIAS_RES><<<dim3(NQ / 256, DIM / 256), 512, 0, stream>>>(
      G, W2T, NQ, DIM, MLPD, b2, RES2, (float*)d_out);
}

// Round 6
// 684.329 us; speedup vs baseline: 1.0327x; 1.0128x over previous
//
#include <hip/hip_runtime.h>
#include <hip/hip_bf16.h>

typedef _Float16 f16;
typedef __attribute__((ext_vector_type(8))) _Float16 f16x8;
typedef __attribute__((ext_vector_type(4))) _Float16 f16x4;
typedef __attribute__((ext_vector_type(4))) float f32x4;

#define DIM 1024
#define HEADS 16
#define DHEAD 64
#define MLPD 4096
#define NQ 16384
#define NW 1024
#define MCHUNK 32

#define WAITV(n) asm volatile("s_waitcnt vmcnt(" #n ")" ::: "memory")
#define WAITL0 asm volatile("s_waitcnt lgkmcnt(0)" ::: "memory")

// ---------------- async global->LDS (16B per lane) ----------------
__device__ __forceinline__ void glds16(const f16* g, f16* l) {
  __builtin_amdgcn_global_load_lds(
      (const __attribute__((address_space(1))) void*)g,
      (__attribute__((address_space(3))) void*)l, 16, 0, 0);
}

// ---------------- LayerNorm(1024): f32 in -> f16 out ----------------
__global__ __launch_bounds__(256) void ln_f16_k(
    const float* __restrict__ X, const float* __restrict__ w,
    const float* __restrict__ b, f16* __restrict__ O) {
  const int row = blockIdx.x;
  const int t = threadIdx.x;
  const float4 v = ((const float4*)(X + (long)row * DIM))[t];
  float s = v.x + v.y + v.z + v.w;
  float s2 = v.x * v.x + v.y * v.y + v.z * v.z + v.w * v.w;
#pragma unroll
  for (int m = 1; m < 64; m <<= 1) {
    s += __shfl_xor(s, m);
    s2 += __shfl_xor(s2, m);
  }
  __shared__ float ps[4], ps2[4];
  const int lane = t & 63, wid = t >> 6;
  if (lane == 0) { ps[wid] = s; ps2[wid] = s2; }
  __syncthreads();
  s = ps[0] + ps[1] + ps[2] + ps[3];
  s2 = ps2[0] + ps2[1] + ps2[2] + ps2[3];
  const float mu = s * (1.0f / DIM);
  const float inv = rsqrtf(s2 * (1.0f / DIM) - mu * mu + 1e-5f);
  const float4 wv = ((const float4*)w)[t];
  const float4 bv = ((const float4*)b)[t];
  f16x4 o;
  o[0] = (f16)((v.x - mu) * inv * wv.x + bv.x);
  o[1] = (f16)((v.y - mu) * inv * wv.y + bv.y);
  o[2] = (f16)((v.z - mu) * inv * wv.z + bv.z);
  o[3] = (f16)((v.w - mu) * inv * wv.w + bv.w);
  *(f16x4*)(O + (long)row * DIM + t * 4) = o;
}

// ---------------- LayerNorm(1024): f16 in -> f16 out ----------------
__global__ __launch_bounds__(256) void ln_f16in_k(
    const f16* __restrict__ X, const float* __restrict__ w,
    const float* __restrict__ b, f16* __restrict__ O) {
  const int row = blockIdx.x;
  const int t = threadIdx.x;
  const f16x4 hv = *(const f16x4*)(X + (long)row * DIM + t * 4);
  const float x0 = (float)hv[0], x1 = (float)hv[1], x2 = (float)hv[2],
              x3 = (float)hv[3];
  float s = x0 + x1 + x2 + x3;
  float s2 = x0 * x0 + x1 * x1 + x2 * x2 + x3 * x3;
#pragma unroll
  for (int m = 1; m < 64; m <<= 1) {
    s += __shfl_xor(s, m);
    s2 += __shfl_xor(s2, m);
  }
  __shared__ float ps[4], ps2[4];
  const int lane = t & 63, wid = t >> 6;
  if (lane == 0) { ps[wid] = s; ps2[wid] = s2; }
  __syncthreads();
  s = ps[0] + ps[1] + ps[2] + ps[3];
  s2 = ps2[0] + ps2[1] + ps2[2] + ps2[3];
  const float mu = s * (1.0f / DIM);
  const float inv = rsqrtf(s2 * (1.0f / DIM) - mu * mu + 1e-5f);
  const float4 wv = ((const float4*)w)[t];
  const float4 bv = ((const float4*)b)[t];
  f16x4 o;
  o[0] = (f16)((x0 - mu) * inv * wv.x + bv.x);
  o[1] = (f16)((x1 - mu) * inv * wv.y + bv.y);
  o[2] = (f16)((x2 - mu) * inv * wv.z + bv.z);
  o[3] = (f16)((x3 - mu) * inv * wv.w + bv.w);
  *(f16x4*)(O + (long)row * DIM + t * 4) = o;
}

// ---------------- transpose + cast f32[R][C] -> f16[C][R] ----------------
__global__ __launch_bounds__(256) void tcast_k(const float* __restrict__ X,
                                               f16* __restrict__ O, int R, int C) {
  __shared__ float tile[32][33];
  const int c0 = blockIdx.x * 32, r0 = blockIdx.y * 32;
  const int tx = threadIdx.x, ty = threadIdx.y;  // (32,8)
#pragma unroll
  for (int j = 0; j < 4; ++j)
    tile[ty + j * 8][tx] = X[(long)(r0 + ty + j * 8) * C + c0 + tx];
  __syncthreads();
#pragma unroll
  for (int j = 0; j < 4; ++j)
    O[(long)(c0 + ty + j * 8) * R + r0 + tx] = (f16)tile[tx][ty + j * 8];
}

// ---------------- M_h partials: Mp[h][ch] = sum_{n in chunk} khat^T v ------------
__global__ __launch_bounds__(256) void calc_m_part_k(const f16* __restrict__ kh,
                                                     const f16* __restrict__ v,
                                                     float* __restrict__ Mp) {
  const int h = blockIdx.x, ch = blockIdx.y;
  const int t = threadIdx.x;
  const int d1 = t >> 2;
  const int d2b = (t & 3) * 16;
  float acc[16] = {};
  const int n0 = ch * (NW / MCHUNK);
#pragma unroll 4
  for (int n = n0; n < n0 + NW / MCHUNK; ++n) {
    const float kv = (float)kh[(long)n * DIM + h * DHEAD + d1];
    const f16x8* vp = (const f16x8*)&v[(long)n * DIM + h * DHEAD + d2b];
    const f16x8 v0 = vp[0], v1 = vp[1];
#pragma unroll
    for (int j = 0; j < 8; ++j) acc[j] += kv * (float)v0[j];
#pragma unroll
    for (int j = 0; j < 8; ++j) acc[8 + j] += kv * (float)v1[j];
  }
  float* o = &Mp[((long)(h * MCHUNK + ch)) * 4096 + d1 * 64 + d2b];
#pragma unroll
  for (int j = 0; j < 16; ++j) o[j] = acc[j];
}

__global__ __launch_bounds__(256) void calc_m_reduce_k(const float* __restrict__ Mp,
                                                       float* __restrict__ Mo) {
  const int h = blockIdx.x;
  const int t = threadIdx.x;
#pragma unroll
  for (int e = t; e < 4096; e += 256) {
    float s = 0.f;
#pragma unroll
    for (int c = 0; c < MCHUNK; ++c)
      s += Mp[((long)(h * MCHUNK + c)) * 4096 + e];
    Mo[h * 4096 + e] = s;
  }
}

// ---------------- W_eff^T[j][i] = sum_d M[h(i)][i%64][d] * wo[h*64+d][j] ----------------
__global__ __launch_bounds__(256) void calc_wefft_k(const float* __restrict__ M,
                                                    const float* __restrict__ wo,
                                                    f16* __restrict__ Wt) {
  const int h = blockIdx.x, jt = blockIdx.y;
  const int t = threadIdx.x;
  const int jl = t & 63;
  const int il0 = (t >> 6) * 16;
  const int j = jt * 64 + jl;
  float acc[16] = {};
  for (int d = 0; d < DHEAD; ++d) {
    const float w = wo[(long)(h * DHEAD + d) * DIM + j];
    const float* mrow = &M[h * 4096 + il0 * 64 + d];
#pragma unroll
    for (int r = 0; r < 16; ++r) acc[r] += mrow[r * 64] * w;
  }
#pragma unroll
  for (int r = 0; r < 16; ++r)
    Wt[(long)j * DIM + h * DHEAD + il0 + r] = (f16)acc[r];
}

// ======================= 256x256 8-phase GEMM ==========================
// Same schedule as R5 (verified-neutral but sound). NEW: M-slab XCD mapping —
// XCD c owns bm-slab [c*gx/8,(c+1)*gx/8); within a slab, dispatch order sweeps
// bm-inner/bn-outer so the ~32 co-resident blocks/XCD share a ~6MB L2 working
// set and A is fetched ONCE chip-wide (was: every XCD pulled all of A).
enum {
  EPI_F16 = 0,   // f16 out
  EPI_L2N = 1,   // per-head l2norm, f16 out
  EPI_ATTN = 2,  // f16 out = acc + bias + f32 resid
  EPI_GELU = 3,  // f16 out = gelu(acc + bias), fast tanh form
  EPI_OUT = 4    // f32 out = acc + bias + (float)f16 resid
};

template <int EPI>
__global__ __launch_bounds__(512, 2) void gemm256(
    const f16* __restrict__ A, const f16* __restrict__ Bt, int M, int N, int K,
    const float* __restrict__ bias, const void* resid, void* out) {
  __shared__ __align__(16) f16 lds[65536];  // 128KB: 2 bufs x {A[2][.],B[2][.]}

  const int tid = threadIdx.x;
  const int lane = tid & 63;
  const int wid = tid >> 6;   // 0..7
  const int wm = wid >> 2;    // 0..1
  const int wn = wid & 3;     // 0..3
  const int l15 = lane & 15;

  // M-slab XCD mapping (hw: block orig -> XCD orig%8)
  int bm, bn;
  {
    const int orig = blockIdx.y * gridDim.x + blockIdx.x;
    if ((gridDim.x & 7) == 0) {
      const int slab = orig & 7;       // XCD
      const int idx = orig >> 3;       // temporal order within XCD
      const int sm = gridDim.x >> 3;   // bm rows per slab
      bm = slab * sm + idx % sm;
      bn = idx / sm;
    } else {
      bm = blockIdx.x;
      bn = blockIdx.y;
    }
  }

  // staging: thread t -> row = (t>>2) (+128), slot = t&3 in a 16KB region;
  // source col pre-XORed with ((t>>3)&3) (both-sides involution w/ ds_read XOR)
  const int scol8 = (((tid & 3) ^ ((tid >> 3) & 3))) * 8;
  const f16* aSrc = A + (long)(bm * 256 + (tid >> 2)) * K + scol8;
  const f16* bSrc = Bt + (long)(bn * 256 + (tid >> 2)) * K + scol8;
  const long hK = (long)128 * K;
  const int tid8 = tid * 8;

  const int rslot8 = (((lane >> 4) ^ ((l15 >> 1) & 3))) * 8;
  const int aRdBase = (wm * 128 + l15) * 32 + rslot8;
  const int bRdBase = 16384 + (wn * 64 + l15) * 32 + rslot8;

  f32x4 acc[8][4] = {};
  const int NT = K >> 6;

  // ---- prologue: t0.A.ks0, t0.B.ks0, t0.A.ks1, t0.B.ks1, t1.A.ks0, t1.B.ks0
  glds16(aSrc, &lds[tid8]);
  glds16(aSrc + hK, &lds[4096 + tid8]);
  glds16(bSrc, &lds[16384 + tid8]);
  glds16(bSrc + hK, &lds[16384 + 4096 + tid8]);
  glds16(aSrc + 32, &lds[8192 + tid8]);
  glds16(aSrc + hK + 32, &lds[8192 + 4096 + tid8]);
  glds16(bSrc + 32, &lds[24576 + tid8]);
  glds16(bSrc + hK + 32, &lds[24576 + 4096 + tid8]);
  glds16(aSrc + 64, &lds[32768 + tid8]);
  glds16(aSrc + hK + 64, &lds[32768 + 4096 + tid8]);
  glds16(bSrc + 64, &lds[32768 + 16384 + tid8]);
  glds16(bSrc + hK + 64, &lds[32768 + 16384 + 4096 + tid8]);
  WAITV(8);
  __builtin_amdgcn_s_barrier();

#define PHASE_CORE(KS, MH, LOADB)                                        \
  {                                                                      \
    const f16* Ap = L + (KS)*8192 + aRdBase + (MH)*2048;                 \
    a[0] = *(const f16x8*)(Ap);                                          \
    a[1] = *(const f16x8*)(Ap + 512);                                    \
    a[2] = *(const f16x8*)(Ap + 1024);                                   \
    a[3] = *(const f16x8*)(Ap + 1536);                                   \
    if (LOADB) {                                                         \
      const f16* Bp = L + (KS)*8192 + bRdBase;                           \
      b[0] = *(const f16x8*)(Bp);                                        \
      b[1] = *(const f16x8*)(Bp + 512);                                  \
      b[2] = *(const f16x8*)(Bp + 1024);                                 \
      b[3] = *(const f16x8*)(Bp + 1536);                                 \
    }                                                                    \
    __builtin_amdgcn_s_barrier();                                        \
    WAITL0;                                                              \
    __builtin_amdgcn_sched_barrier(0);                                   \
    __builtin_amdgcn_s_setprio(1);                                       \
    _Pragma("unroll") for (int j = 0; j < 4; ++j)                        \
        _Pragma("unroll") for (int nj = 0; nj < 4; ++nj)                 \
            acc[(MH)*4 + j][nj] = __builtin_amdgcn_mfma_f32_16x16x32_f16(\
                a[j], b[nj], acc[(MH)*4 + j][nj], 0, 0, 0);              \
    __builtin_amdgcn_s_setprio(0);                                       \
  }

  for (int g = 0; g < NT; ++g) {
    f16* L = &lds[(g & 1) * 32768];
    f16* Lo = &lds[((g & 1) ^ 1) * 32768];
    const long ko1 = (long)(g + 1) * 64;
    const long ko2 = (long)(g + 2) * 64;
    const bool s1 = (g + 1) < NT, s2 = (g + 2) < NT;
    f16x8 a[4], b[4];

    if (s1) {
      glds16(aSrc + ko1 + 32, Lo + 8192 + tid8);
      glds16(aSrc + hK + ko1 + 32, Lo + 8192 + 4096 + tid8);
    }
    PHASE_CORE(0, 0, 1);
    __builtin_amdgcn_s_barrier();

    if (s1) {
      glds16(bSrc + ko1 + 32, Lo + 24576 + tid8);
      glds16(bSrc + hK + ko1 + 32, Lo + 24576 + 4096 + tid8);
    }
    PHASE_CORE(0, 1, 0);
    if (s1) { WAITV(8); } else { WAITV(0); }
    __builtin_amdgcn_s_barrier();

    if (s2) {
      glds16(aSrc + ko2, L + tid8);
      glds16(aSrc + hK + ko2, L + 4096 + tid8);
    }
    PHASE_CORE(1, 0, 1);
    __builtin_amdgcn_s_barrier();

    if (s2) {
      glds16(bSrc + ko2, L + 16384 + tid8);
      glds16(bSrc + hK + ko2, L + 16384 + 4096 + tid8);
    }
    PHASE_CORE(1, 1, 0);
    if (s2) { WAITV(8); } else if (s1) { WAITV(4); }
    __builtin_amdgcn_s_barrier();
  }
#undef PHASE_CORE

  // epilogue
  const int r0 = bm * 256 + wm * 128;
  const int c0 = bn * 256 + wn * 64;  // == one head for EPI_L2N
  const int lr = (lane >> 4) * 4;
  const int lc = l15;

#pragma unroll
  for (int mi = 0; mi < 8; ++mi) {
#pragma unroll
    for (int i = 0; i < 4; ++i) {
      const long r = r0 + mi * 16 + lr + i;
      if (EPI == EPI_L2N) {
        float ss = 0.f;
#pragma unroll
        for (int nj = 0; nj < 4; ++nj) {
          const float x = acc[mi][nj][i];
          ss += x * x;
        }
        ss += __shfl_xor(ss, 1);
        ss += __shfl_xor(ss, 2);
        ss += __shfl_xor(ss, 4);
        ss += __shfl_xor(ss, 8);
        const float inv = 1.0f / fmaxf(sqrtf(ss), 1e-12f);
#pragma unroll
        for (int nj = 0; nj < 4; ++nj)
          ((f16*)out)[r * N + c0 + nj * 16 + lc] = (f16)(acc[mi][nj][i] * inv);
      } else if (EPI == EPI_F16) {
#pragma unroll
        for (int nj = 0; nj < 4; ++nj)
          ((f16*)out)[r * N + c0 + nj * 16 + lc] = (f16)acc[mi][nj][i];
      } else if (EPI == EPI_ATTN) {
#pragma unroll
        for (int nj = 0; nj < 4; ++nj) {
          const long c = c0 + nj * 16 + lc;
          ((f16*)out)[r * N + c] =
              (f16)(acc[mi][nj][i] + bias[c] + ((const float*)resid)[r * N + c]);
        }
      } else if (EPI == EPI_GELU) {
#pragma unroll
        for (int nj = 0; nj < 4; ++nj) {
          const long c = c0 + nj * 16 + lc;
          const float x = acc[mi][nj][i] + bias[c];
          // tanh-form gelu, overflow-clamped (|err| <= ~1e-3, budget 0.29)
          const float u = 0.7978845608028654f * (x + 0.044715f * x * x * x);
          const float z = __expf(fminf(-2.0f * u, 88.0f));
          const float th = (1.0f - z) / (1.0f + z);
          ((f16*)out)[r * N + c] = (f16)(0.5f * x * (1.0f + th));
        }
      } else {  // EPI_OUT
#pragma unroll
        for (int nj = 0; nj < 4; ++nj) {
          const long c = c0 + nj * 16 + lc;
          ((float*)out)[r * N + c] =
              acc[mi][nj][i] + bias[c] + (float)((const f16*)resid)[r * N + c];
        }
      }
    }
  }
}

extern "C" void kernel_launch(void* const* d_in, const int* in_sizes, int n_in,
                              void* d_out, int out_size, void* d_ws, size_t ws_size,
                              hipStream_t stream) {
  (void)in_sizes; (void)n_in; (void)out_size;
  const float* queries = (const float*)d_in[0];
  const float* prototypes = (const float*)d_in[1];
  const float* ln1_w = (const float*)d_in[2];
  const float* ln1_b = (const float*)d_in[3];
  const float* wq = (const float*)d_in[4];
  const float* wk = (const float*)d_in[5];
  const float* wv = (const float*)d_in[6];
  const float* wo = (const float*)d_in[7];
  const float* bo = (const float*)d_in[8];
  const float* ln2_w = (const float*)d_in[9];
  const float* ln2_b = (const float*)d_in[10];
  const float* w1 = (const float*)d_in[11];
  const float* b1 = (const float*)d_in[12];
  const float* w2 = (const float*)d_in[13];
  const float* b2 = (const float*)d_in[14];

  char* ws = (char*)d_ws;
  const size_t MB = 1024ull * 1024ull;
  if (ws_size < 160ull * MB) return;  // layout needs 160MB

  // transient region (dead before MLP; G aliases it)
  f16* QN = (f16*)(ws + 0);             // 32MB [16384][1024]
  f16* QHAT = (f16*)(ws + 32 * MB);     // 32MB
  f16* PN = (f16*)(ws + 64 * MB);       // 2MB
  f16* WQT = (f16*)(ws + 66 * MB);      // 2MB
  f16* WKT = (f16*)(ws + 68 * MB);      // 2MB
  f16* WVT = (f16*)(ws + 70 * MB);      // 2MB
  f16* KHAT = (f16*)(ws + 72 * MB);     // 2MB
  f16* VBF = (f16*)(ws + 74 * MB);      // 2MB
  float* Mbuf = (float*)(ws + 76 * MB); // 256KB
  f16* WEFFT = (f16*)(ws + 77 * MB);    // 2MB
  float* Mpart = (float*)(ws + 0);      // 8MB, aliases QN (dead by then)
  // persistent region
  f16* G = (f16*)(ws + 0);              // 64MB [8192][4096] chunk, aliases QN+QHAT
  f16* RES2 = (f16*)(ws + 80 * MB);     // 32MB [16384][1024]
  f16* HBF = (f16*)(ws + 112 * MB);     // 32MB
  f16* W1T = (f16*)(ws + 144 * MB);     // 8MB [4096][1024]
  f16* W2T = (f16*)(ws + 152 * MB);     // 8MB [1024][4096]

  // LN1 + cast
  ln_f16_k<<<NQ, 256, 0, stream>>>(queries, ln1_w, ln1_b, QN);
  ln_f16_k<<<NW, 256, 0, stream>>>(prototypes, ln1_w, ln1_b, PN);
  // weight transpose-casts
  tcast_k<<<dim3(32, 32), dim3(32, 8), 0, stream>>>(wq, WQT, DIM, DIM);
  tcast_k<<<dim3(32, 32), dim3(32, 8), 0, stream>>>(wk, WKT, DIM, DIM);
  tcast_k<<<dim3(32, 32), dim3(32, 8), 0, stream>>>(wv, WVT, DIM, DIM);
  tcast_k<<<dim3(128, 32), dim3(32, 8), 0, stream>>>(w1, W1T, DIM, MLPD);
  tcast_k<<<dim3(32, 128), dim3(32, 8), 0, stream>>>(w2, W2T, MLPD, DIM);

  // projections (+fused per-head l2norm for q,k)
  gemm256<EPI_L2N><<<dim3(NQ / 256, DIM / 256), 512, 0, stream>>>(
      QN, WQT, NQ, DIM, DIM, nullptr, nullptr, QHAT);
  gemm256<EPI_L2N><<<dim3(NW / 256, DIM / 256), 512, 0, stream>>>(
      PN, WKT, NW, DIM, DIM, nullptr, nullptr, KHAT);
  gemm256<EPI_F16><<<dim3(NW / 256, DIM / 256), 512, 0, stream>>>(
      PN, WVT, NW, DIM, DIM, nullptr, nullptr, VBF);

  // attention collapse: M_h = khat^T v (split-K) ; W_eff^T = (blockdiag(M) @ wo)^T
  calc_m_part_k<<<dim3(HEADS, MCHUNK), 256, 0, stream>>>(KHAT, VBF, Mpart);
  calc_m_reduce_k<<<HEADS, 256, 0, stream>>>(Mpart, Mbuf);
  calc_wefft_k<<<dim3(HEADS, 16), 256, 0, stream>>>(Mbuf, wo, WEFFT);

  // attn-out + wo + bias + residual -> RES2 (f16)
  gemm256<EPI_ATTN><<<dim3(NQ / 256, DIM / 256), 512, 0, stream>>>(
      QHAT, WEFFT, NQ, DIM, DIM, bo, queries, RES2);

  // LN2 (f16 in)
  ln_f16in_k<<<NQ, 256, 0, stream>>>(RES2, ln2_w, ln2_b, HBF);

  // MLP in 2 row-chunks of 8192 (G stays LLC-hot)
  for (int c = 0; c < 2; ++c) {
    const long ro = (long)c * 8192;
    gemm256<EPI_GELU><<<dim3(32, MLPD / 256), 512, 0, stream>>>(
        HBF + ro * DIM, W1T, 8192, MLPD, DIM, b1, nullptr, G);
    gemm256<EPI_OUT><<<dim3(32, DIM / 256), 512, 0, stream>>>(
        G, W2T, 8192, DIM, MLPD, b2, RES2 + ro * DIM,
        (float*)d_out + ro * DIM);
  }
}

// Round 7
// 655.712 us; speedup vs baseline: 1.0778x; 1.0436x over previous
//
#include <hip/hip_runtime.h>
#include <hip/hip_bf16.h>

typedef _Float16 f16;
typedef __attribute__((ext_vector_type(8))) _Float16 f16x8;
typedef __attribute__((ext_vector_type(4))) _Float16 f16x4;
typedef __attribute__((ext_vector_type(4))) float f32x4;

#define DIM 1024
#define HEADS 16
#define DHEAD 64
#define MLPD 4096
#define NQ 16384
#define NW 1024
#define MCHUNK 32

#define WAITV(n) asm volatile("s_waitcnt vmcnt(" #n ")" ::: "memory")
#define WAITL0 asm volatile("s_waitcnt lgkmcnt(0)" ::: "memory")

// ---------------- async global->LDS (16B per lane) ----------------
__device__ __forceinline__ void glds16(const f16* g, f16* l) {
  __builtin_amdgcn_global_load_lds(
      (const __attribute__((address_space(1))) void*)g,
      (__attribute__((address_space(3))) void*)l, 16, 0, 0);
}

// ---------------- LayerNorm(1024): f32 in -> f16 out ----------------
__global__ __launch_bounds__(256) void ln_f16_k(
    const float* __restrict__ X, const float* __restrict__ w,
    const float* __restrict__ b, f16* __restrict__ O) {
  const int row = blockIdx.x;
  const int t = threadIdx.x;
  const float4 v = ((const float4*)(X + (long)row * DIM))[t];
  float s = v.x + v.y + v.z + v.w;
  float s2 = v.x * v.x + v.y * v.y + v.z * v.z + v.w * v.w;
#pragma unroll
  for (int m = 1; m < 64; m <<= 1) {
    s += __shfl_xor(s, m);
    s2 += __shfl_xor(s2, m);
  }
  __shared__ float ps[4], ps2[4];
  const int lane = t & 63, wid = t >> 6;
  if (lane == 0) { ps[wid] = s; ps2[wid] = s2; }
  __syncthreads();
  s = ps[0] + ps[1] + ps[2] + ps[3];
  s2 = ps2[0] + ps2[1] + ps2[2] + ps2[3];
  const float mu = s * (1.0f / DIM);
  const float inv = rsqrtf(s2 * (1.0f / DIM) - mu * mu + 1e-5f);
  const float4 wv = ((const float4*)w)[t];
  const float4 bv = ((const float4*)b)[t];
  f16x4 o;
  o[0] = (f16)((v.x - mu) * inv * wv.x + bv.x);
  o[1] = (f16)((v.y - mu) * inv * wv.y + bv.y);
  o[2] = (f16)((v.z - mu) * inv * wv.z + bv.z);
  o[3] = (f16)((v.w - mu) * inv * wv.w + bv.w);
  *(f16x4*)(O + (long)row * DIM + t * 4) = o;
}

// ---------------- transpose + cast f32[R][C] -> f16[C][R] ----------------
__global__ __launch_bounds__(256) void tcast_k(const float* __restrict__ X,
                                               f16* __restrict__ O, int R, int C) {
  __shared__ float tile[32][33];
  const int c0 = blockIdx.x * 32, r0 = blockIdx.y * 32;
  const int tx = threadIdx.x, ty = threadIdx.y;  // (32,8)
#pragma unroll
  for (int j = 0; j < 4; ++j)
    tile[ty + j * 8][tx] = X[(long)(r0 + ty + j * 8) * C + c0 + tx];
  __syncthreads();
#pragma unroll
  for (int j = 0; j < 4; ++j)
    O[(long)(c0 + ty + j * 8) * R + r0 + tx] = (f16)tile[tx][ty + j * 8];
}

// ---------------- M_h partials: Mp[h][ch] = sum_{n in chunk} khat^T v ------------
__global__ __launch_bounds__(256) void calc_m_part_k(const f16* __restrict__ kh,
                                                     const f16* __restrict__ v,
                                                     float* __restrict__ Mp) {
  const int h = blockIdx.x, ch = blockIdx.y;
  const int t = threadIdx.x;
  const int d1 = t >> 2;
  const int d2b = (t & 3) * 16;
  float acc[16] = {};
  const int n0 = ch * (NW / MCHUNK);
#pragma unroll 4
  for (int n = n0; n < n0 + NW / MCHUNK; ++n) {
    const float kv = (float)kh[(long)n * DIM + h * DHEAD + d1];
    const f16x8* vp = (const f16x8*)&v[(long)n * DIM + h * DHEAD + d2b];
    const f16x8 v0 = vp[0], v1 = vp[1];
#pragma unroll
    for (int j = 0; j < 8; ++j) acc[j] += kv * (float)v0[j];
#pragma unroll
    for (int j = 0; j < 8; ++j) acc[8 + j] += kv * (float)v1[j];
  }
  float* o = &Mp[((long)(h * MCHUNK + ch)) * 4096 + d1 * 64 + d2b];
#pragma unroll
  for (int j = 0; j < 16; ++j) o[j] = acc[j];
}

__global__ __launch_bounds__(256) void calc_m_reduce_k(const float* __restrict__ Mp,
                                                       float* __restrict__ Mo) {
  const int h = blockIdx.x;
  const int t = threadIdx.x;
#pragma unroll
  for (int e = t; e < 4096; e += 256) {
    float s = 0.f;
#pragma unroll
    for (int c = 0; c < MCHUNK; ++c)
      s += Mp[((long)(h * MCHUNK + c)) * 4096 + e];
    Mo[h * 4096 + e] = s;
  }
}

// ---------------- W_eff^T[j][i] = sum_d M[h(i)][i%64][d] * wo[h*64+d][j] ----------------
__global__ __launch_bounds__(256) void calc_wefft_k(const float* __restrict__ M,
                                                    const float* __restrict__ wo,
                                                    f16* __restrict__ Wt) {
  const int h = blockIdx.x, jt = blockIdx.y;
  const int t = threadIdx.x;
  const int jl = t & 63;
  const int il0 = (t >> 6) * 16;
  const int j = jt * 64 + jl;
  float acc[16] = {};
  for (int d = 0; d < DHEAD; ++d) {
    const float w = wo[(long)(h * DHEAD + d) * DIM + j];
    const float* mrow = &M[h * 4096 + il0 * 64 + d];
#pragma unroll
    for (int r = 0; r < 16; ++r) acc[r] += mrow[r * 64] * w;
  }
#pragma unroll
  for (int r = 0; r < 16; ++r)
    Wt[(long)j * DIM + h * DHEAD + il0 + r] = (f16)acc[r];
}

// ======================= 256x256 8-phase GEMM ==========================
// 8-phase counted-vmcnt schedule (R5) + M-slab XCD mapping (R6: FETCH 270->74MB
// verified). This round: all grids restored to >=256 blocks (R6's chunked MLP2
// ran 128 blocks = half the chip idle, Occupancy 10.5%).
enum {
  EPI_F16 = 0,       // f16 out
  EPI_L2N = 1,       // per-head l2norm, f16 out
  EPI_BIAS_RES = 2,  // f32 out = acc + bias + f32 resid (out may alias resid)
  EPI_GELU = 3       // f16 out = gelu(acc + bias), fast tanh form
};

template <int EPI>
__global__ __launch_bounds__(512, 2) void gemm256(
    const f16* __restrict__ A, const f16* __restrict__ Bt, int M, int N, int K,
    const float* __restrict__ bias, const float* resid, void* out) {
  __shared__ __align__(16) f16 lds[65536];  // 128KB: 2 bufs x {A[2][.],B[2][.]}

  const int tid = threadIdx.x;
  const int lane = tid & 63;
  const int wid = tid >> 6;   // 0..7
  const int wm = wid >> 2;    // 0..1
  const int wn = wid & 3;     // 0..3
  const int l15 = lane & 15;

  // M-slab XCD mapping (hw: block orig -> XCD orig%8): XCD owns a contiguous
  // bm-slab, sweeps bn with bm-inner order -> A fetched once chip-wide.
  int bm, bn;
  {
    const int orig = blockIdx.y * gridDim.x + blockIdx.x;
    if ((gridDim.x & 7) == 0) {
      const int slab = orig & 7;       // XCD
      const int idx = orig >> 3;       // temporal order within XCD
      const int sm = gridDim.x >> 3;   // bm rows per slab
      bm = slab * sm + idx % sm;
      bn = idx / sm;
    } else {
      bm = blockIdx.x;
      bn = blockIdx.y;
    }
  }

  // staging: thread t -> row = (t>>2) (+128), slot = t&3 in a 16KB region;
  // source col pre-XORed with ((t>>3)&3) (both-sides involution w/ ds_read XOR)
  const int scol8 = (((tid & 3) ^ ((tid >> 3) & 3))) * 8;
  const f16* aSrc = A + (long)(bm * 256 + (tid >> 2)) * K + scol8;
  const f16* bSrc = Bt + (long)(bn * 256 + (tid >> 2)) * K + scol8;
  const long hK = (long)128 * K;
  const int tid8 = tid * 8;

  const int rslot8 = (((lane >> 4) ^ ((l15 >> 1) & 3))) * 8;
  const int aRdBase = (wm * 128 + l15) * 32 + rslot8;
  const int bRdBase = 16384 + (wn * 64 + l15) * 32 + rslot8;

  f32x4 acc[8][4] = {};
  const int NT = K >> 6;

  // ---- prologue: t0.A.ks0, t0.B.ks0, t0.A.ks1, t0.B.ks1, t1.A.ks0, t1.B.ks0
  glds16(aSrc, &lds[tid8]);
  glds16(aSrc + hK, &lds[4096 + tid8]);
  glds16(bSrc, &lds[16384 + tid8]);
  glds16(bSrc + hK, &lds[16384 + 4096 + tid8]);
  glds16(aSrc + 32, &lds[8192 + tid8]);
  glds16(aSrc + hK + 32, &lds[8192 + 4096 + tid8]);
  glds16(bSrc + 32, &lds[24576 + tid8]);
  glds16(bSrc + hK + 32, &lds[24576 + 4096 + tid8]);
  glds16(aSrc + 64, &lds[32768 + tid8]);
  glds16(aSrc + hK + 64, &lds[32768 + 4096 + tid8]);
  glds16(bSrc + 64, &lds[32768 + 16384 + tid8]);
  glds16(bSrc + hK + 64, &lds[32768 + 16384 + 4096 + tid8]);
  WAITV(8);
  __builtin_amdgcn_s_barrier();

#define PHASE_CORE(KS, MH, LOADB)                                        \
  {                                                                      \
    const f16* Ap = L + (KS)*8192 + aRdBase + (MH)*2048;                 \
    a[0] = *(const f16x8*)(Ap);                                          \
    a[1] = *(const f16x8*)(Ap + 512);                                    \
    a[2] = *(const f16x8*)(Ap + 1024);                                   \
    a[3] = *(const f16x8*)(Ap + 1536);                                   \
    if (LOADB) {                                                         \
      const f16* Bp = L + (KS)*8192 + bRdBase;                           \
      b[0] = *(const f16x8*)(Bp);                                        \
      b[1] = *(const f16x8*)(Bp + 512);                                  \
      b[2] = *(const f16x8*)(Bp + 1024);                                 \
      b[3] = *(const f16x8*)(Bp + 1536);                                 \
    }                                                                    \
    __builtin_amdgcn_s_barrier();                                        \
    WAITL0;                                                              \
    __builtin_amdgcn_sched_barrier(0);                                   \
    __builtin_amdgcn_s_setprio(1);                                       \
    _Pragma("unroll") for (int j = 0; j < 4; ++j)                        \
        _Pragma("unroll") for (int nj = 0; nj < 4; ++nj)                 \
            acc[(MH)*4 + j][nj] = __builtin_amdgcn_mfma_f32_16x16x32_f16(\
                a[j], b[nj], acc[(MH)*4 + j][nj], 0, 0, 0);              \
    __builtin_amdgcn_s_setprio(0);                                       \
  }

  for (int g = 0; g < NT; ++g) {
    f16* L = &lds[(g & 1) * 32768];
    f16* Lo = &lds[((g & 1) ^ 1) * 32768];
    const long ko1 = (long)(g + 1) * 64;
    const long ko2 = (long)(g + 2) * 64;
    const bool s1 = (g + 1) < NT, s2 = (g + 2) < NT;
    f16x8 a[4], b[4];

    if (s1) {
      glds16(aSrc + ko1 + 32, Lo + 8192 + tid8);
      glds16(aSrc + hK + ko1 + 32, Lo + 8192 + 4096 + tid8);
    }
    PHASE_CORE(0, 0, 1);
    __builtin_amdgcn_s_barrier();

    if (s1) {
      glds16(bSrc + ko1 + 32, Lo + 24576 + tid8);
      glds16(bSrc + hK + ko1 + 32, Lo + 24576 + 4096 + tid8);
    }
    PHASE_CORE(0, 1, 0);
    if (s1) { WAITV(8); } else { WAITV(0); }
    __builtin_amdgcn_s_barrier();

    if (s2) {
      glds16(aSrc + ko2, L + tid8);
      glds16(aSrc + hK + ko2, L + 4096 + tid8);
    }
    PHASE_CORE(1, 0, 1);
    __builtin_amdgcn_s_barrier();

    if (s2) {
      glds16(bSrc + ko2, L + 16384 + tid8);
      glds16(bSrc + hK + ko2, L + 16384 + 4096 + tid8);
    }
    PHASE_CORE(1, 1, 0);
    if (s2) { WAITV(8); } else if (s1) { WAITV(4); }
    __builtin_amdgcn_s_barrier();
  }
#undef PHASE_CORE

  // epilogue
  const int r0 = bm * 256 + wm * 128;
  const int c0 = bn * 256 + wn * 64;  // == one head for EPI_L2N
  const int lr = (lane >> 4) * 4;
  const int lc = l15;

#pragma unroll
  for (int mi = 0; mi < 8; ++mi) {
#pragma unroll
    for (int i = 0; i < 4; ++i) {
      const long r = r0 + mi * 16 + lr + i;
      if (EPI == EPI_L2N) {
        float ss = 0.f;
#pragma unroll
        for (int nj = 0; nj < 4; ++nj) {
          const float x = acc[mi][nj][i];
          ss += x * x;
        }
        ss += __shfl_xor(ss, 1);
        ss += __shfl_xor(ss, 2);
        ss += __shfl_xor(ss, 4);
        ss += __shfl_xor(ss, 8);
        const float inv = 1.0f / fmaxf(sqrtf(ss), 1e-12f);
#pragma unroll
        for (int nj = 0; nj < 4; ++nj)
          ((f16*)out)[r * N + c0 + nj * 16 + lc] = (f16)(acc[mi][nj][i] * inv);
      } else if (EPI == EPI_F16) {
#pragma unroll
        for (int nj = 0; nj < 4; ++nj)
          ((f16*)out)[r * N + c0 + nj * 16 + lc] = (f16)acc[mi][nj][i];
      } else if (EPI == EPI_BIAS_RES) {
#pragma unroll
        for (int nj = 0; nj < 4; ++nj) {
          const long c = c0 + nj * 16 + lc;
          ((float*)out)[r * N + c] = acc[mi][nj][i] + bias[c] + resid[r * N + c];
        }
      } else {  // EPI_GELU (fast tanh form, |err|<=~1e-3 vs erf, budget 0.29)
#pragma unroll
        for (int nj = 0; nj < 4; ++nj) {
          const long c = c0 + nj * 16 + lc;
          const float x = acc[mi][nj][i] + bias[c];
          const float u = 0.7978845608028654f * (x + 0.044715f * x * x * x);
          const float z = __expf(fminf(-2.0f * u, 88.0f));
          const float th = (1.0f - z) / (1.0f + z);
          ((f16*)out)[r * N + c] = (f16)(0.5f * x * (1.0f + th));
        }
      }
    }
  }
}

extern "C" void kernel_launch(void* const* d_in, const int* in_sizes, int n_in,
                              void* d_out, int out_size, void* d_ws, size_t ws_size,
                              hipStream_t stream) {
  (void)in_sizes; (void)n_in; (void)out_size;
  const float* queries = (const float*)d_in[0];
  const float* prototypes = (const float*)d_in[1];
  const float* ln1_w = (const float*)d_in[2];
  const float* ln1_b = (const float*)d_in[3];
  const float* wq = (const float*)d_in[4];
  const float* wk = (const float*)d_in[5];
  const float* wv = (const float*)d_in[6];
  const float* wo = (const float*)d_in[7];
  const float* bo = (const float*)d_in[8];
  const float* ln2_w = (const float*)d_in[9];
  const float* ln2_b = (const float*)d_in[10];
  const float* w1 = (const float*)d_in[11];
  const float* b1 = (const float*)d_in[12];
  const float* w2 = (const float*)d_in[13];
  const float* b2 = (const float*)d_in[14];

  char* ws = (char*)d_ws;
  const size_t MB = 1024ull * 1024ull;
  if (ws_size < 176ull * MB) return;  // layout needs 176MB

  // transient region (dead before MLP; G aliases it)
  f16* QN = (f16*)(ws + 0);             // 32MB [16384][1024]
  f16* QHAT = (f16*)(ws + 32 * MB);     // 32MB
  f16* PN = (f16*)(ws + 64 * MB);       // 2MB
  f16* WQT = (f16*)(ws + 66 * MB);      // 2MB
  f16* WKT = (f16*)(ws + 68 * MB);      // 2MB
  f16* WVT = (f16*)(ws + 70 * MB);      // 2MB
  f16* KHAT = (f16*)(ws + 72 * MB);     // 2MB
  f16* VBF = (f16*)(ws + 74 * MB);      // 2MB
  float* Mbuf = (float*)(ws + 76 * MB); // 256KB
  f16* WEFFT = (f16*)(ws + 77 * MB);    // 2MB
  float* Mpart = (float*)(ws + 0);      // 8MB, aliases QN (dead by then)
  // persistent region
  f16* G = (f16*)(ws + 0);              // 128MB [16384][4096], aliases transients
  f16* HBF = (f16*)(ws + 128 * MB);     // 32MB
  f16* W1T = (f16*)(ws + 160 * MB);     // 8MB [4096][1024]
  f16* W2T = (f16*)(ws + 168 * MB);     // 8MB [1024][4096]
  float* RES2 = (float*)d_out;          // residual2 lives in d_out (f32, 64MB)

  // LN1 + cast
  ln_f16_k<<<NQ, 256, 0, stream>>>(queries, ln1_w, ln1_b, QN);
  ln_f16_k<<<NW, 256, 0, stream>>>(prototypes, ln1_w, ln1_b, PN);
  // weight transpose-casts
  tcast_k<<<dim3(32, 32), dim3(32, 8), 0, stream>>>(wq, WQT, DIM, DIM);
  tcast_k<<<dim3(32, 32), dim3(32, 8), 0, stream>>>(wk, WKT, DIM, DIM);
  tcast_k<<<dim3(32, 32), dim3(32, 8), 0, stream>>>(wv, WVT, DIM, DIM);
  tcast_k<<<dim3(128, 32), dim3(32, 8), 0, stream>>>(w1, W1T, DIM, MLPD);
  tcast_k<<<dim3(32, 128), dim3(32, 8), 0, stream>>>(w2, W2T, MLPD, DIM);

  // projections (+fused per-head l2norm for q,k)
  gemm256<EPI_L2N><<<dim3(NQ / 256, DIM / 256), 512, 0, stream>>>(
      QN, WQT, NQ, DIM, DIM, nullptr, nullptr, QHAT);
  gemm256<EPI_L2N><<<dim3(NW / 256, DIM / 256), 512, 0, stream>>>(
      PN, WKT, NW, DIM, DIM, nullptr, nullptr, KHAT);
  gemm256<EPI_F16><<<dim3(NW / 256, DIM / 256), 512, 0, stream>>>(
      PN, WVT, NW, DIM, DIM, nullptr, nullptr, VBF);

  // attention collapse: M_h = khat^T v (split-K) ; W_eff^T = (blockdiag(M) @ wo)^T
  calc_m_part_k<<<dim3(HEADS, MCHUNK), 256, 0, stream>>>(KHAT, VBF, Mpart);
  calc_m_reduce_k<<<HEADS, 256, 0, stream>>>(Mpart, Mbuf);
  calc_wefft_k<<<dim3(HEADS, 16), 256, 0, stream>>>(Mbuf, wo, WEFFT);

  // attn-out + wo + bias + residual -> RES2 (f32, in d_out)
  gemm256<EPI_BIAS_RES><<<dim3(NQ / 256, DIM / 256), 512, 0, stream>>>(
      QHAT, WEFFT, NQ, DIM, DIM, bo, queries, RES2);

  // LN2 (reads d_out f32)
  ln_f16_k<<<NQ, 256, 0, stream>>>(RES2, ln2_w, ln2_b, HBF);

  // MLP, unchunked: full grids (1024 / 256 blocks)
  gemm256<EPI_GELU><<<dim3(NQ / 256, MLPD / 256), 512, 0, stream>>>(
      HBF, W1T, NQ, MLPD, DIM, b1, nullptr, G);
  gemm256<EPI_BIAS_RES><<<dim3(NQ / 256, DIM / 256), 512, 0, stream>>>(
      G, W2T, NQ, DIM, MLPD, b2, RES2, (float*)d_out);
}

// Round 8
// 636.381 us; speedup vs baseline: 1.1105x; 1.0304x over previous
//
#include <hip/hip_runtime.h>
#include <hip/hip_bf16.h>

typedef _Float16 f16;
typedef __attribute__((ext_vector_type(8))) _Float16 f16x8;
typedef __attribute__((ext_vector_type(4))) _Float16 f16x4;
typedef __attribute__((ext_vector_type(4))) float f32x4;

#define DIM 1024
#define HEADS 16
#define DHEAD 64
#define MLPD 4096
#define NQ 16384
#define NW 1024
#define MCHUNK 32

// ---------------- async global->LDS (16B per lane) ----------------
__device__ __forceinline__ void glds16(const f16* g, f16* l) {
  __builtin_amdgcn_global_load_lds(
      (const __attribute__((address_space(1))) void*)g,
      (__attribute__((address_space(3))) void*)l, 16, 0, 0);
}

// ---------------- LayerNorm(1024): f32 in -> f16 out ----------------
__global__ __launch_bounds__(256) void ln_f16_k(
    const float* __restrict__ X, const float* __restrict__ w,
    const float* __restrict__ b, f16* __restrict__ O) {
  const int row = blockIdx.x;
  const int t = threadIdx.x;
  const float4 v = ((const float4*)(X + (long)row * DIM))[t];
  float s = v.x + v.y + v.z + v.w;
  float s2 = v.x * v.x + v.y * v.y + v.z * v.z + v.w * v.w;
#pragma unroll
  for (int m = 1; m < 64; m <<= 1) {
    s += __shfl_xor(s, m);
    s2 += __shfl_xor(s2, m);
  }
  __shared__ float ps[4], ps2[4];
  const int lane = t & 63, wid = t >> 6;
  if (lane == 0) { ps[wid] = s; ps2[wid] = s2; }
  __syncthreads();
  s = ps[0] + ps[1] + ps[2] + ps[3];
  s2 = ps2[0] + ps2[1] + ps2[2] + ps2[3];
  const float mu = s * (1.0f / DIM);
  const float inv = rsqrtf(s2 * (1.0f / DIM) - mu * mu + 1e-5f);
  const float4 wv = ((const float4*)w)[t];
  const float4 bv = ((const float4*)b)[t];
  f16x4 o;
  o[0] = (f16)((v.x - mu) * inv * wv.x + bv.x);
  o[1] = (f16)((v.y - mu) * inv * wv.y + bv.y);
  o[2] = (f16)((v.z - mu) * inv * wv.z + bv.z);
  o[3] = (f16)((v.w - mu) * inv * wv.w + bv.w);
  *(f16x4*)(O + (long)row * DIM + t * 4) = o;
}

// ---------------- transpose + cast f32[R][C] -> f16[C][R] ----------------
__global__ __launch_bounds__(256) void tcast_k(const float* __restrict__ X,
                                               f16* __restrict__ O, int R, int C) {
  __shared__ float tile[32][33];
  const int c0 = blockIdx.x * 32, r0 = blockIdx.y * 32;
  const int tx = threadIdx.x, ty = threadIdx.y;  // (32,8)
#pragma unroll
  for (int j = 0; j < 4; ++j)
    tile[ty + j * 8][tx] = X[(long)(r0 + ty + j * 8) * C + c0 + tx];
  __syncthreads();
#pragma unroll
  for (int j = 0; j < 4; ++j)
    O[(long)(c0 + ty + j * 8) * R + r0 + tx] = (f16)tile[tx][ty + j * 8];
}

// ---------------- M_h partials: Mp[h][ch] = sum_{n in chunk} khat^T v ------------
__global__ __launch_bounds__(256) void calc_m_part_k(const f16* __restrict__ kh,
                                                     const f16* __restrict__ v,
                                                     float* __restrict__ Mp) {
  const int h = blockIdx.x, ch = blockIdx.y;
  const int t = threadIdx.x;
  const int d1 = t >> 2;
  const int d2b = (t & 3) * 16;
  float acc[16] = {};
  const int n0 = ch * (NW / MCHUNK);
#pragma unroll 4
  for (int n = n0; n < n0 + NW / MCHUNK; ++n) {
    const float kv = (float)kh[(long)n * DIM + h * DHEAD + d1];
    const f16x8* vp = (const f16x8*)&v[(long)n * DIM + h * DHEAD + d2b];
    const f16x8 v0 = vp[0], v1 = vp[1];
#pragma unroll
    for (int j = 0; j < 8; ++j) acc[j] += kv * (float)v0[j];
#pragma unroll
    for (int j = 0; j < 8; ++j) acc[8 + j] += kv * (float)v1[j];
  }
  float* o = &Mp[((long)(h * MCHUNK + ch)) * 4096 + d1 * 64 + d2b];
#pragma unroll
  for (int j = 0; j < 16; ++j) o[j] = acc[j];
}

__global__ __launch_bounds__(256) void calc_m_reduce_k(const float* __restrict__ Mp,
                                                       float* __restrict__ Mo) {
  const int h = blockIdx.x;
  const int t = threadIdx.x;
#pragma unroll
  for (int e = t; e < 4096; e += 256) {
    float s = 0.f;
#pragma unroll
    for (int c = 0; c < MCHUNK; ++c)
      s += Mp[((long)(h * MCHUNK + c)) * 4096 + e];
    Mo[h * 4096 + e] = s;
  }
}

// ---------------- W_eff^T[j][i] = sum_d M[h(i)][i%64][d] * wo[h*64+d][j] ----------------
__global__ __launch_bounds__(256) void calc_wefft_k(const float* __restrict__ M,
                                                    const float* __restrict__ wo,
                                                    f16* __restrict__ Wt) {
  const int h = blockIdx.x, jt = blockIdx.y;
  const int t = threadIdx.x;
  const int jl = t & 63;
  const int il0 = (t >> 6) * 16;
  const int j = jt * 64 + jl;
  float acc[16] = {};
  for (int d = 0; d < DHEAD; ++d) {
    const float w = wo[(long)(h * DHEAD + d) * DIM + j];
    const float* mrow = &M[h * 4096 + il0 * 64 + d];
#pragma unroll
    for (int r = 0; r < 16; ++r) acc[r] += mrow[r * 64] * w;
  }
#pragma unroll
  for (int r = 0; r < 16; ++r)
    Wt[(long)j * DIM + h * DHEAD + il0 + r] = (f16)acc[r];
}

// ======================= 256x256 one-barrier-per-tile GEMM ==========================
// BK=64, 512 thr = 8 waves (2Mx4N), per-wave 128x64 out. LDS 128KB = 2 bufs.
// Within a tile: waves READ only buf L, glds WRITES only buf Lo -> no intra-tile
// barrier needed. Tile body is straight-line: stage-next + {4-frag ds_read groups
// one ahead of 16-MFMA bursts}; compiler inserts fine-grained lgkmcnt. Boundary
// = single __syncthreads() (drains vm+lgkm; tile g+1 landed; all waves done).
// R7 diagnosis: the old per-phase barrier+lgkm(0) serialized the CU-wide LDS-read
// burst with the MFMA burst (~1940cy/phase vs 620cy MFMA) -> MfmaUtil stuck ~29%.
enum {
  EPI_F16 = 0,       // f16 out
  EPI_L2N = 1,       // per-head l2norm, f16 out
  EPI_BIAS_RES = 2,  // f32 out = acc + bias + f32 resid (out may alias resid)
  EPI_GELU = 3       // f16 out = gelu(acc + bias), fast tanh form
};

template <int EPI>
__global__ __launch_bounds__(512, 2) void gemm256(
    const f16* __restrict__ A, const f16* __restrict__ Bt, int M, int N, int K,
    const float* __restrict__ bias, const float* resid, void* out) {
  __shared__ __align__(16) f16 lds[65536];  // 128KB: 2 bufs x {A[2][256][32], B[2][256][32]}

  const int tid = threadIdx.x;
  const int lane = tid & 63;
  const int wid = tid >> 6;   // 0..7
  const int wm = wid >> 2;    // 0..1
  const int wn = wid & 3;     // 0..3
  const int l15 = lane & 15;

  // M-slab XCD mapping (hw: block orig -> XCD orig%8): XCD owns a contiguous
  // bm-slab, sweeps bn with bm-inner order -> A fetched once chip-wide (R6: ✓).
  int bm, bn;
  {
    const int orig = blockIdx.y * gridDim.x + blockIdx.x;
    if ((gridDim.x & 7) == 0) {
      const int slab = orig & 7;
      const int idx = orig >> 3;
      const int sm = gridDim.x >> 3;
      bm = slab * sm + idx % sm;
      bn = idx / sm;
    } else {
      bm = blockIdx.x;
      bn = blockIdx.y;
    }
  }

  // staging: thread t -> row = (t>>2) (+128), slot = t&3 in a 16KB region;
  // source col pre-XORed with ((t>>3)&3) (both-sides involution w/ ds_read XOR)
  const int scol8 = (((tid & 3) ^ ((tid >> 3) & 3))) * 8;
  const f16* aSrc = A + (long)(bm * 256 + (tid >> 2)) * K + scol8;
  const f16* bSrc = Bt + (long)(bn * 256 + (tid >> 2)) * K + scol8;
  const long hK = (long)128 * K;
  const int tid8 = tid * 8;

  const int rslot8 = (((lane >> 4) ^ ((l15 >> 1) & 3))) * 8;
  const int aRdBase = (wm * 128 + l15) * 32 + rslot8;
  const int bRdBase = 16384 + (wn * 64 + l15) * 32 + rslot8;

  f32x4 acc[8][4] = {};
  const int NT = K >> 6;

#define STAGE_A0(Ld, ko)                              \
  glds16(aSrc + (ko), (Ld) + tid8);                   \
  glds16(aSrc + hK + (ko), (Ld) + 4096 + tid8)
#define STAGE_A1(Ld, ko)                              \
  glds16(aSrc + (ko) + 32, (Ld) + 8192 + tid8);       \
  glds16(aSrc + hK + (ko) + 32, (Ld) + 8192 + 4096 + tid8)
#define STAGE_B0(Ld, ko)                              \
  glds16(bSrc + (ko), (Ld) + 16384 + tid8);           \
  glds16(bSrc + hK + (ko), (Ld) + 16384 + 4096 + tid8)
#define STAGE_B1(Ld, ko)                              \
  glds16(bSrc + (ko) + 32, (Ld) + 24576 + tid8);      \
  glds16(bSrc + hK + (ko) + 32, (Ld) + 24576 + 4096 + tid8)

#define BURST(AF, BF, MB)                                                 \
  __builtin_amdgcn_s_setprio(1);                                          \
  _Pragma("unroll") for (int j = 0; j < 4; ++j)                           \
      _Pragma("unroll") for (int nj = 0; nj < 4; ++nj)                    \
          acc[(MB) + j][nj] = __builtin_amdgcn_mfma_f32_16x16x32_f16(     \
              AF[j], BF[nj], acc[(MB) + j][nj], 0, 0, 0);                 \
  __builtin_amdgcn_s_setprio(0)

  // prologue: stage tile 0 fully into buf0, sync, pre-read first frag groups
  STAGE_A0(lds, 0);
  STAGE_B0(lds, 0);
  STAGE_A1(lds, 0);
  STAGE_B1(lds, 0);
  __syncthreads();

  f16x8 bA[4], bB[4], aA[4], aB[4], aC[4], aD[4];
#pragma unroll
  for (int j = 0; j < 4; ++j) bA[j] = *(const f16x8*)&lds[bRdBase + j * 512];
#pragma unroll
  for (int j = 0; j < 4; ++j) aA[j] = *(const f16x8*)&lds[aRdBase + j * 512];

  for (int g = 0; g < NT; ++g) {
    f16* L = &lds[(g & 1) * 32768];
    f16* Lo = &lds[((g & 1) ^ 1) * 32768];
    const long ko1 = (long)(g + 1) * 64;
    const bool s1 = (g + 1) < NT;

    if (s1) { STAGE_A0(Lo, ko1); STAGE_B0(Lo, ko1); }
    // read (ks0, mh1) ahead of the first burst
#pragma unroll
    for (int j = 0; j < 4; ++j)
      aB[j] = *(const f16x8*)&L[aRdBase + 2048 + j * 512];
    BURST(aA, bA, 0);          // ks0, mh0
    if (s1) { STAGE_A1(Lo, ko1); STAGE_B1(Lo, ko1); }
    // reads for ks1 ahead of the second burst
#pragma unroll
    for (int j = 0; j < 4; ++j)
      bB[j] = *(const f16x8*)&L[8192 + bRdBase + j * 512];
#pragma unroll
    for (int j = 0; j < 4; ++j)
      aC[j] = *(const f16x8*)&L[8192 + aRdBase + j * 512];
    BURST(aB, bA, 4);          // ks0, mh1
#pragma unroll
    for (int j = 0; j < 4; ++j)
      aD[j] = *(const f16x8*)&L[8192 + aRdBase + 2048 + j * 512];
    BURST(aC, bB, 0);          // ks1, mh0
    BURST(aD, bB, 4);          // ks1, mh1

    __syncthreads();           // drains vm+lgkm: tile g+1 landed, buf L free
    if (s1) {
#pragma unroll
      for (int j = 0; j < 4; ++j) bA[j] = *(const f16x8*)&Lo[bRdBase + j * 512];
#pragma unroll
      for (int j = 0; j < 4; ++j) aA[j] = *(const f16x8*)&Lo[aRdBase + j * 512];
    }
  }
#undef STAGE_A0
#undef STAGE_A1
#undef STAGE_B0
#undef STAGE_B1
#undef BURST

  // epilogue
  const int r0 = bm * 256 + wm * 128;
  const int c0 = bn * 256 + wn * 64;  // == one head for EPI_L2N
  const int lr = (lane >> 4) * 4;
  const int lc = l15;

#pragma unroll
  for (int mi = 0; mi < 8; ++mi) {
#pragma unroll
    for (int i = 0; i < 4; ++i) {
      const long r = r0 + mi * 16 + lr + i;
      if (EPI == EPI_L2N) {
        float ss = 0.f;
#pragma unroll
        for (int nj = 0; nj < 4; ++nj) {
          const float x = acc[mi][nj][i];
          ss += x * x;
        }
        ss += __shfl_xor(ss, 1);
        ss += __shfl_xor(ss, 2);
        ss += __shfl_xor(ss, 4);
        ss += __shfl_xor(ss, 8);
        const float inv = 1.0f / fmaxf(sqrtf(ss), 1e-12f);
#pragma unroll
        for (int nj = 0; nj < 4; ++nj)
          ((f16*)out)[r * N + c0 + nj * 16 + lc] = (f16)(acc[mi][nj][i] * inv);
      } else if (EPI == EPI_F16) {
#pragma unroll
        for (int nj = 0; nj < 4; ++nj)
          ((f16*)out)[r * N + c0 + nj * 16 + lc] = (f16)acc[mi][nj][i];
      } else if (EPI == EPI_BIAS_RES) {
#pragma unroll
        for (int nj = 0; nj < 4; ++nj) {
          const long c = c0 + nj * 16 + lc;
          ((float*)out)[r * N + c] = acc[mi][nj][i] + bias[c] + resid[r * N + c];
        }
      } else {  // EPI_GELU (fast tanh form, |err|<=~1e-3 vs erf, budget 0.29)
#pragma unroll
        for (int nj = 0; nj < 4; ++nj) {
          const long c = c0 + nj * 16 + lc;
          const float x = acc[mi][nj][i] + bias[c];
          const float u = 0.7978845608028654f * (x + 0.044715f * x * x * x);
          const float z = __expf(fminf(-2.0f * u, 88.0f));
          const float th = (1.0f - z) / (1.0f + z);
          ((f16*)out)[r * N + c] = (f16)(0.5f * x * (1.0f + th));
        }
      }
    }
  }
}

extern "C" void kernel_launch(void* const* d_in, const int* in_sizes, int n_in,
                              void* d_out, int out_size, void* d_ws, size_t ws_size,
                              hipStream_t stream) {
  (void)in_sizes; (void)n_in; (void)out_size;
  const float* queries = (const float*)d_in[0];
  const float* prototypes = (const float*)d_in[1];
  const float* ln1_w = (const float*)d_in[2];
  const float* ln1_b = (const float*)d_in[3];
  const float* wq = (const float*)d_in[4];
  const float* wk = (const float*)d_in[5];
  const float* wv = (const float*)d_in[6];
  const float* wo = (const float*)d_in[7];
  const float* bo = (const float*)d_in[8];
  const float* ln2_w = (const float*)d_in[9];
  const float* ln2_b = (const float*)d_in[10];
  const float* w1 = (const float*)d_in[11];
  const float* b1 = (const float*)d_in[12];
  const float* w2 = (const float*)d_in[13];
  const float* b2 = (const float*)d_in[14];

  char* ws = (char*)d_ws;
  const size_t MB = 1024ull * 1024ull;
  if (ws_size < 176ull * MB) return;  // layout needs 176MB

  // transient region (dead before MLP; G aliases it)
  f16* QN = (f16*)(ws + 0);             // 32MB [16384][1024]
  f16* QHAT = (f16*)(ws + 32 * MB);     // 32MB
  f16* PN = (f16*)(ws + 64 * MB);       // 2MB
  f16* WQT = (f16*)(ws + 66 * MB);      // 2MB
  f16* WKT = (f16*)(ws + 68 * MB);      // 2MB
  f16* WVT = (f16*)(ws + 70 * MB);      // 2MB
  f16* KHAT = (f16*)(ws + 72 * MB);     // 2MB
  f16* VBF = (f16*)(ws + 74 * MB);      // 2MB
  float* Mbuf = (float*)(ws + 76 * MB); // 256KB
  f16* WEFFT = (f16*)(ws + 77 * MB);    // 2MB
  float* Mpart = (float*)(ws + 0);      // 8MB, aliases QN (dead by then)
  // persistent region
  f16* G = (f16*)(ws + 0);              // 128MB [16384][4096], aliases transients
  f16* HBF = (f16*)(ws + 128 * MB);     // 32MB
  f16* W1T = (f16*)(ws + 160 * MB);     // 8MB [4096][1024]
  f16* W2T = (f16*)(ws + 168 * MB);     // 8MB [1024][4096]
  float* RES2 = (float*)d_out;          // residual2 lives in d_out (f32, 64MB)

  // LN1 + cast
  ln_f16_k<<<NQ, 256, 0, stream>>>(queries, ln1_w, ln1_b, QN);
  ln_f16_k<<<NW, 256, 0, stream>>>(prototypes, ln1_w, ln1_b, PN);
  // weight transpose-casts
  tcast_k<<<dim3(32, 32), dim3(32, 8), 0, stream>>>(wq, WQT, DIM, DIM);
  tcast_k<<<dim3(32, 32), dim3(32, 8), 0, stream>>>(wk, WKT, DIM, DIM);
  tcast_k<<<dim3(32, 32), dim3(32, 8), 0, stream>>>(wv, WVT, DIM, DIM);
  tcast_k<<<dim3(128, 32), dim3(32, 8), 0, stream>>>(w1, W1T, DIM, MLPD);
  tcast_k<<<dim3(32, 128), dim3(32, 8), 0, stream>>>(w2, W2T, MLPD, DIM);

  // projections (+fused per-head l2norm for q,k)
  gemm256<EPI_L2N><<<dim3(NQ / 256, DIM / 256), 512, 0, stream>>>(
      QN, WQT, NQ, DIM, DIM, nullptr, nullptr, QHAT);
  gemm256<EPI_L2N><<<dim3(NW / 256, DIM / 256), 512, 0, stream>>>(
      PN, WKT, NW, DIM, DIM, nullptr, nullptr, KHAT);
  gemm256<EPI_F16><<<dim3(NW / 256, DIM / 256), 512, 0, stream>>>(
      PN, WVT, NW, DIM, DIM, nullptr, nullptr, VBF);

  // attention collapse: M_h = khat^T v (split-K) ; W_eff^T = (blockdiag(M) @ wo)^T
  calc_m_part_k<<<dim3(HEADS, MCHUNK), 256, 0, stream>>>(KHAT, VBF, Mpart);
  calc_m_reduce_k<<<HEADS, 256, 0, stream>>>(Mpart, Mbuf);
  calc_wefft_k<<<dim3(HEADS, 16), 256, 0, stream>>>(Mbuf, wo, WEFFT);

  // attn-out + wo + bias + residual -> RES2 (f32, in d_out)
  gemm256<EPI_BIAS_RES><<<dim3(NQ / 256, DIM / 256), 512, 0, stream>>>(
      QHAT, WEFFT, NQ, DIM, DIM, bo, queries, RES2);

  // LN2 (reads d_out f32)
  ln_f16_k<<<NQ, 256, 0, stream>>>(RES2, ln2_w, ln2_b, HBF);

  // MLP, unchunked: full grids (1024 / 256 blocks)
  gemm256<EPI_GELU><<<dim3(NQ / 256, MLPD / 256), 512, 0, stream>>>(
      HBF, W1T, NQ, MLPD, DIM, b1, nullptr, G);
  gemm256<EPI_BIAS_RES><<<dim3(NQ / 256, DIM / 256), 512, 0, stream>>>(
      G, W2T, NQ, DIM, MLPD, b2, RES2, (float*)d_out);
}